// Round 1
// baseline (4485.507 us; speedup 1.0000x reference)
//
#include <hip/hip_runtime.h>

#define N_NODES 100000
#define F_IN    256
#define H_DIM   128
#define C_DIM   64
#define E_EDGES 1600000
#define EP_EDGES 500000

// ---------------------------------------------------------------------------
// Degree / normalization
// ---------------------------------------------------------------------------
__global__ __launch_bounds__(256) void init_deg_kernel(float* __restrict__ deg) {
    int i = blockIdx.x * 256 + threadIdx.x;
    if (i < N_NODES) deg[i] = 1.0f;  // self-loop
}

__global__ __launch_bounds__(256) void count_deg_kernel(const int* __restrict__ dst,
                                                        float* __restrict__ deg) {
    int e = blockIdx.x * 256 + threadIdx.x;
    if (e < E_EDGES) atomicAdd(&deg[dst[e]], 1.0f);
}

__global__ __launch_bounds__(256) void finalize_dis_kernel(float* __restrict__ deg) {
    int i = blockIdx.x * 256 + threadIdx.x;
    if (i < N_NODES) deg[i] = rsqrtf(deg[i]);  // in-place: deg -> dis
}

// ---------------------------------------------------------------------------
// GEMM1: T[N,128] = X[N,256] @ W1[256,128]   (fp32 vector ALU, tiled)
// block: 256 threads, tile 128 rows x 128 cols, K-tile 16; thread = 8x8
// ---------------------------------------------------------------------------
__global__ __launch_bounds__(256) void gemm1_kernel(const float* __restrict__ X,
                                                    const float* __restrict__ W,
                                                    float* __restrict__ T,
                                                    int nrows) {
    __shared__ float Xs[16][132];   // [k][row], padded stride 132
    __shared__ float Ws[16][128];   // [k][col]
    const int t = threadIdx.x;
    const int row0 = blockIdx.x * 128;
    const int ty = t >> 4;   // 0..15 (8-row group)
    const int tx = t & 15;   // 0..15 (4-col group, two halves)

    float acc[8][8];
#pragma unroll
    for (int i = 0; i < 8; ++i)
#pragma unroll
        for (int j = 0; j < 8; ++j) acc[i][j] = 0.0f;

    for (int k0 = 0; k0 < F_IN; k0 += 16) {
        // load X tile 128x16 (512 float4, 2 per thread), transpose into Xs
#pragma unroll
        for (int qi = 0; qi < 2; ++qi) {
            int q = t + qi * 256;
            int r = q >> 2, c4 = q & 3;
            int row = row0 + r;
            float4 v = make_float4(0.f, 0.f, 0.f, 0.f);
            if (row < nrows)
                v = *(const float4*)&X[(long long)row * F_IN + k0 + c4 * 4];
            Xs[c4 * 4 + 0][r] = v.x;
            Xs[c4 * 4 + 1][r] = v.y;
            Xs[c4 * 4 + 2][r] = v.z;
            Xs[c4 * 4 + 3][r] = v.w;
        }
        // load W tile 16x128 (512 float4, 2 per thread)
#pragma unroll
        for (int qi = 0; qi < 2; ++qi) {
            int q = t + qi * 256;
            int r = q >> 5, c4 = q & 31;
            *(float4*)&Ws[r][c4 * 4] = *(const float4*)&W[(k0 + r) * H_DIM + c4 * 4];
        }
        __syncthreads();
#pragma unroll
        for (int k = 0; k < 16; ++k) {
            float4 a0 = *(const float4*)&Xs[k][ty * 8];
            float4 a1 = *(const float4*)&Xs[k][ty * 8 + 4];
            float4 b0 = *(const float4*)&Ws[k][tx * 4];
            float4 b1 = *(const float4*)&Ws[k][tx * 4 + 64];
            float a[8] = {a0.x, a0.y, a0.z, a0.w, a1.x, a1.y, a1.z, a1.w};
            float b[8] = {b0.x, b0.y, b0.z, b0.w, b1.x, b1.y, b1.z, b1.w};
#pragma unroll
            for (int i = 0; i < 8; ++i)
#pragma unroll
                for (int j = 0; j < 8; ++j) acc[i][j] = fmaf(a[i], b[j], acc[i][j]);
        }
        __syncthreads();
    }
#pragma unroll
    for (int i = 0; i < 8; ++i) {
        int row = row0 + ty * 8 + i;
        if (row < nrows) {
            float4 c0 = make_float4(acc[i][0], acc[i][1], acc[i][2], acc[i][3]);
            float4 c1 = make_float4(acc[i][4], acc[i][5], acc[i][6], acc[i][7]);
            *(float4*)&T[(long long)row * H_DIM + tx * 4] = c0;
            *(float4*)&T[(long long)row * H_DIM + 64 + tx * 4] = c1;
        }
    }
}

// ---------------------------------------------------------------------------
// GEMM2: T2[N,64] = relu(AGG1[N,128] + b1) @ W2[128,64]
// block: 256 threads, tile 128 rows x 64 cols, K-tile 16; thread = 8x4
// ---------------------------------------------------------------------------
__global__ __launch_bounds__(256) void gemm2_kernel(const float* __restrict__ A,
                                                    const float* __restrict__ b1,
                                                    const float* __restrict__ W,
                                                    float* __restrict__ T,
                                                    int nrows) {
    __shared__ float Xs[16][132];
    __shared__ float Ws[16][64];
    const int t = threadIdx.x;
    const int row0 = blockIdx.x * 128;
    const int ty = t >> 4;   // 0..15
    const int tx = t & 15;   // 0..15 -> cols tx*4..tx*4+3

    float acc[8][4];
#pragma unroll
    for (int i = 0; i < 8; ++i)
#pragma unroll
        for (int j = 0; j < 4; ++j) acc[i][j] = 0.0f;

    for (int k0 = 0; k0 < H_DIM; k0 += 16) {
        // X tile 128x16 with fused bias+relu
#pragma unroll
        for (int qi = 0; qi < 2; ++qi) {
            int q = t + qi * 256;
            int r = q >> 2, c4 = q & 3;
            int row = row0 + r;
            float4 v = make_float4(0.f, 0.f, 0.f, 0.f);
            if (row < nrows) {
                float4 av = *(const float4*)&A[(long long)row * H_DIM + k0 + c4 * 4];
                float4 bv = *(const float4*)&b1[k0 + c4 * 4];
                v.x = fmaxf(av.x + bv.x, 0.f);
                v.y = fmaxf(av.y + bv.y, 0.f);
                v.z = fmaxf(av.z + bv.z, 0.f);
                v.w = fmaxf(av.w + bv.w, 0.f);
            }
            Xs[c4 * 4 + 0][r] = v.x;
            Xs[c4 * 4 + 1][r] = v.y;
            Xs[c4 * 4 + 2][r] = v.z;
            Xs[c4 * 4 + 3][r] = v.w;
        }
        // W tile 16x64 (256 float4, 1 per thread)
        {
            int r = t >> 4, c4 = t & 15;
            *(float4*)&Ws[r][c4 * 4] = *(const float4*)&W[(k0 + r) * C_DIM + c4 * 4];
        }
        __syncthreads();
#pragma unroll
        for (int k = 0; k < 16; ++k) {
            float4 a0 = *(const float4*)&Xs[k][ty * 8];
            float4 a1 = *(const float4*)&Xs[k][ty * 8 + 4];
            float4 b0 = *(const float4*)&Ws[k][tx * 4];
            float a[8] = {a0.x, a0.y, a0.z, a0.w, a1.x, a1.y, a1.z, a1.w};
            float b[4] = {b0.x, b0.y, b0.z, b0.w};
#pragma unroll
            for (int i = 0; i < 8; ++i)
#pragma unroll
                for (int j = 0; j < 4; ++j) acc[i][j] = fmaf(a[i], b[j], acc[i][j]);
        }
        __syncthreads();
    }
#pragma unroll
    for (int i = 0; i < 8; ++i) {
        int row = row0 + ty * 8 + i;
        if (row < nrows) {
            float4 c0 = make_float4(acc[i][0], acc[i][1], acc[i][2], acc[i][3]);
            *(float4*)&T[(long long)row * C_DIM + tx * 4] = c0;
        }
    }
}

// ---------------------------------------------------------------------------
// Self-loop init: AGG[i,:] = T[i,:] * dis[i]^2    (SHIFT = log2(F/4))
// ---------------------------------------------------------------------------
template <int SHIFT>
__global__ __launch_bounds__(256) void selfloop_kernel(const float* __restrict__ t,
                                                       const float* __restrict__ dis,
                                                       float* __restrict__ agg) {
    unsigned idx = blockIdx.x * 256u + threadIdx.x;
    if (idx >= (unsigned)(N_NODES << SHIFT)) return;
    int i = idx >> SHIFT;
    float ds = dis[i];
    float c = ds * ds;
    float4 v = ((const float4*)t)[idx];
    float4 r = make_float4(v.x * c, v.y * c, v.z * c, v.w * c);
    ((float4*)agg)[idx] = r;
}

// ---------------------------------------------------------------------------
// Edge scatter: AGG[dst,:] += T[src,:] * dis[src]*dis[dst]
// thread = one float4 of one edge's message; SHIFT = log2(F/4)
// ---------------------------------------------------------------------------
template <int SHIFT>
__global__ __launch_bounds__(256) void scatter_kernel(const float* __restrict__ t,
                                                      const float* __restrict__ dis,
                                                      const int* __restrict__ src,
                                                      const int* __restrict__ dst,
                                                      float* __restrict__ agg) {
    unsigned idx = blockIdx.x * 256u + threadIdx.x;
    if (idx >= (unsigned)E_EDGES << SHIFT) return;
    int e = idx >> SHIFT;
    int q = idx & ((1 << SHIFT) - 1);
    int s = src[e], d = dst[e];
    float c = dis[s] * dis[d];
    float4 v = ((const float4*)t)[((long long)s << SHIFT) + q];
    float* base = agg + ((((long long)d << SHIFT) + q) << 2);
    atomicAdd(base + 0, v.x * c);
    atomicAdd(base + 1, v.y * c);
    atomicAdd(base + 2, v.z * c);
    atomicAdd(base + 3, v.w * c);
}

// ---------------------------------------------------------------------------
// Bias add (layer 2 finalize, in place): H2 = AGG2 + b2
// ---------------------------------------------------------------------------
__global__ __launch_bounds__(256) void bias_add_kernel(float* __restrict__ agg,
                                                       const float* __restrict__ b2) {
    unsigned idx = blockIdx.x * 256u + threadIdx.x;
    if (idx >= (unsigned)(N_NODES * (C_DIM / 4))) return;
    int c4 = idx & 15;
    float4 v = ((float4*)agg)[idx];
    float4 b = ((const float4*)b2)[c4];
    v.x += b.x; v.y += b.y; v.z += b.z; v.w += b.w;
    ((float4*)agg)[idx] = v;
}

// ---------------------------------------------------------------------------
// Scoring: one wave (64 lanes) per test edge; dot over 64 features
// ---------------------------------------------------------------------------
__global__ __launch_bounds__(256) void score_kernel(const float* __restrict__ h2,
                                                    const int* __restrict__ pos,
                                                    const int* __restrict__ neg,
                                                    float* __restrict__ out) {
    int w = (blockIdx.x * 256 + threadIdx.x) >> 6;   // wave id = edge id
    int lane = threadIdx.x & 63;
    if (w >= 2 * EP_EDGES) return;
    int i, j;
    if (w < EP_EDGES) {
        j = pos[w];              // tei[0] (src)
        i = pos[EP_EDGES + w];   // tei[1] (dst)
    } else {
        j = neg[w - EP_EDGES];
        i = neg[w];
    }
    float v = h2[(long long)i * C_DIM + lane] * h2[(long long)j * C_DIM + lane];
#pragma unroll
    for (int o = 32; o > 0; o >>= 1) v += __shfl_down(v, o);
    if (lane == 0) out[w] = v;
}

// ---------------------------------------------------------------------------
extern "C" void kernel_launch(void* const* d_in, const int* in_sizes, int n_in,
                              void* d_out, int out_size, void* d_ws, size_t ws_size,
                              hipStream_t stream) {
    const float* x  = (const float*)d_in[0];
    // d_in[1] = masked_nodes (unused by reference output)
    const int* pos  = (const int*)d_in[2];
    const int* neg  = (const int*)d_in[3];
    const int* ei   = (const int*)d_in[4];
    const float* W1 = (const float*)d_in[5];
    const float* b1 = (const float*)d_in[6];
    const float* W2 = (const float*)d_in[7];
    const float* b2 = (const float*)d_in[8];
    float* out = (float*)d_out;

    char* ws = (char*)d_ws;
    float* dis = (float*)ws;                                    // N floats (deg -> dis)
    float* t   = (float*)(ws + 400000);                         // N*128 floats (t1, then t2)
    float* agg = (float*)(ws + 400000 + 51200000);              // N*128 floats (agg1, then agg2/h2)

    const int* esrc = ei;
    const int* edst = ei + E_EDGES;

    // degrees -> dis = rsqrt(deg+1)
    init_deg_kernel<<<(N_NODES + 255) / 256, 256, 0, stream>>>(dis);
    count_deg_kernel<<<E_EDGES / 256, 256, 0, stream>>>(edst, dis);
    finalize_dis_kernel<<<(N_NODES + 255) / 256, 256, 0, stream>>>(dis);

    // layer 1
    gemm1_kernel<<<(N_NODES + 127) / 128, 256, 0, stream>>>(x, W1, t, N_NODES);
    selfloop_kernel<5><<<(N_NODES * 32) / 256, 256, 0, stream>>>(t, dis, agg);
    scatter_kernel<5><<<(E_EDGES / 256) * 32, 256, 0, stream>>>(t, dis, esrc, edst, agg);

    // layer 2 (bias1+relu fused into gemm2's A-load)
    gemm2_kernel<<<(N_NODES + 127) / 128, 256, 0, stream>>>(agg, b1, W2, t, N_NODES);
    selfloop_kernel<4><<<(N_NODES * 16) / 256, 256, 0, stream>>>(t, dis, agg);
    // NOTE: selfloop<4> writes agg[0..N*64) which overlaps old agg1 — agg1 fully
    // consumed by gemm2 before this launches (same stream, serialized).
    scatter_kernel<4><<<(E_EDGES / 256) * 16, 256, 0, stream>>>(t, dis, esrc, edst, agg);
    bias_add_kernel<<<(N_NODES * 16) / 256, 256, 0, stream>>>(agg, b2);

    // scoring
    score_kernel<<<(2 * EP_EDGES * 64) / 256, 256, 0, stream>>>(agg, pos, neg, out);

    // second output: zeros [2, 2*EP]
    hipMemsetAsync(out + 2 * EP_EDGES, 0, (size_t)4 * EP_EDGES * sizeof(float), stream);
}

// Round 2
// 833.118 us; speedup vs baseline: 5.3840x; 5.3840x over previous
//
#include <hip/hip_runtime.h>

#define N_NODES 100000
#define F_IN    256
#define H_DIM   128
#define C_DIM   64
#define E_EDGES 1600000
#define EP_EDGES 500000

// ---------------------------------------------------------------------------
// CSR build: histogram -> scan -> fill
// ---------------------------------------------------------------------------
__global__ __launch_bounds__(256) void hist_kernel(const int* __restrict__ dst,
                                                   int* __restrict__ counts) {
    int e = blockIdx.x * 256 + threadIdx.x;
    if (e < E_EDGES) atomicAdd(&counts[dst[e]], 1);
}

__global__ __launch_bounds__(256) void dis_kernel(const int* __restrict__ counts,
                                                  float* __restrict__ dis) {
    int i = blockIdx.x * 256 + threadIdx.x;
    if (i < N_NODES) dis[i] = rsqrtf((float)counts[i] + 1.0f);  // +1 self-loop
}

// per-block inclusive scan of counts -> row_ptr[i+1]; block totals -> blocksum
__global__ __launch_bounds__(256) void scan1_kernel(const int* __restrict__ counts,
                                                    int* __restrict__ row_ptr,
                                                    int* __restrict__ blocksum) {
    __shared__ int sh[256];
    int t = threadIdx.x;
    int i = blockIdx.x * 256 + t;
    int v = (i < N_NODES) ? counts[i] : 0;
    sh[t] = v;
    __syncthreads();
#pragma unroll
    for (int off = 1; off < 256; off <<= 1) {
        int u = (t >= off) ? sh[t - off] : 0;
        __syncthreads();
        sh[t] += u;
        __syncthreads();
    }
    if (i < N_NODES) row_ptr[i + 1] = sh[t];
    if (t == 255) blocksum[blockIdx.x] = sh[255];
}

// single-block exclusive scan of blocksum (nb <= 512)
__global__ __launch_bounds__(512) void scan2_kernel(int* __restrict__ blocksum, int nb) {
    __shared__ int sh[512];
    int t = threadIdx.x;
    sh[t] = (t < nb) ? blocksum[t] : 0;
    __syncthreads();
#pragma unroll
    for (int off = 1; off < 512; off <<= 1) {
        int u = (t >= off) ? sh[t - off] : 0;
        __syncthreads();
        sh[t] += u;
        __syncthreads();
    }
    if (t < nb) blocksum[t] = (t == 0) ? 0 : sh[t - 1];
}

// add block offsets; emit cursor[i] = exclusive prefix (fill start)
__global__ __launch_bounds__(256) void scan3_kernel(const int* __restrict__ counts,
                                                    int* __restrict__ row_ptr,
                                                    const int* __restrict__ blocksum,
                                                    int* __restrict__ cursor) {
    int i = blockIdx.x * 256 + threadIdx.x;
    if (i >= N_NODES) return;
    int incl = row_ptr[i + 1] + blocksum[blockIdx.x];
    row_ptr[i + 1] = incl;
    cursor[i] = incl - counts[i];
    if (i == 0) row_ptr[0] = 0;
}

__global__ __launch_bounds__(256) void fill_kernel(const int* __restrict__ src,
                                                   const int* __restrict__ dst,
                                                   int* __restrict__ cursor,
                                                   int* __restrict__ csr_src) {
    int e = blockIdx.x * 256 + threadIdx.x;
    if (e >= E_EDGES) return;
    int j = atomicAdd(&cursor[dst[e]], 1);
    csr_src[j] = src[e];
}

// ---------------------------------------------------------------------------
// GEMM1: T[N,128] = X[N,256] @ W1[256,128]   (fp32 vector ALU, tiled)
// ---------------------------------------------------------------------------
__global__ __launch_bounds__(256) void gemm1_kernel(const float* __restrict__ X,
                                                    const float* __restrict__ W,
                                                    float* __restrict__ T,
                                                    int nrows) {
    __shared__ float Xs[16][132];
    __shared__ float Ws[16][128];
    const int t = threadIdx.x;
    const int row0 = blockIdx.x * 128;
    const int ty = t >> 4;
    const int tx = t & 15;

    float acc[8][8];
#pragma unroll
    for (int i = 0; i < 8; ++i)
#pragma unroll
        for (int j = 0; j < 8; ++j) acc[i][j] = 0.0f;

    for (int k0 = 0; k0 < F_IN; k0 += 16) {
#pragma unroll
        for (int qi = 0; qi < 2; ++qi) {
            int q = t + qi * 256;
            int r = q >> 2, c4 = q & 3;
            int row = row0 + r;
            float4 v = make_float4(0.f, 0.f, 0.f, 0.f);
            if (row < nrows)
                v = *(const float4*)&X[(long long)row * F_IN + k0 + c4 * 4];
            Xs[c4 * 4 + 0][r] = v.x;
            Xs[c4 * 4 + 1][r] = v.y;
            Xs[c4 * 4 + 2][r] = v.z;
            Xs[c4 * 4 + 3][r] = v.w;
        }
#pragma unroll
        for (int qi = 0; qi < 2; ++qi) {
            int q = t + qi * 256;
            int r = q >> 5, c4 = q & 31;
            *(float4*)&Ws[r][c4 * 4] = *(const float4*)&W[(k0 + r) * H_DIM + c4 * 4];
        }
        __syncthreads();
#pragma unroll
        for (int k = 0; k < 16; ++k) {
            float4 a0 = *(const float4*)&Xs[k][ty * 8];
            float4 a1 = *(const float4*)&Xs[k][ty * 8 + 4];
            float4 b0 = *(const float4*)&Ws[k][tx * 4];
            float4 b1 = *(const float4*)&Ws[k][tx * 4 + 64];
            float a[8] = {a0.x, a0.y, a0.z, a0.w, a1.x, a1.y, a1.z, a1.w};
            float b[8] = {b0.x, b0.y, b0.z, b0.w, b1.x, b1.y, b1.z, b1.w};
#pragma unroll
            for (int i = 0; i < 8; ++i)
#pragma unroll
                for (int j = 0; j < 8; ++j) acc[i][j] = fmaf(a[i], b[j], acc[i][j]);
        }
        __syncthreads();
    }
#pragma unroll
    for (int i = 0; i < 8; ++i) {
        int row = row0 + ty * 8 + i;
        if (row < nrows) {
            float4 c0 = make_float4(acc[i][0], acc[i][1], acc[i][2], acc[i][3]);
            float4 c1 = make_float4(acc[i][4], acc[i][5], acc[i][6], acc[i][7]);
            *(float4*)&T[(long long)row * H_DIM + tx * 4] = c0;
            *(float4*)&T[(long long)row * H_DIM + 64 + tx * 4] = c1;
        }
    }
}

// ---------------------------------------------------------------------------
// GEMM2: T2[N,64] = relu(AGG1[N,128] + b1) @ W2[128,64]
// ---------------------------------------------------------------------------
__global__ __launch_bounds__(256) void gemm2_kernel(const float* __restrict__ A,
                                                    const float* __restrict__ b1,
                                                    const float* __restrict__ W,
                                                    float* __restrict__ T,
                                                    int nrows) {
    __shared__ float Xs[16][132];
    __shared__ float Ws[16][64];
    const int t = threadIdx.x;
    const int row0 = blockIdx.x * 128;
    const int ty = t >> 4;
    const int tx = t & 15;

    float acc[8][4];
#pragma unroll
    for (int i = 0; i < 8; ++i)
#pragma unroll
        for (int j = 0; j < 4; ++j) acc[i][j] = 0.0f;

    for (int k0 = 0; k0 < H_DIM; k0 += 16) {
#pragma unroll
        for (int qi = 0; qi < 2; ++qi) {
            int q = t + qi * 256;
            int r = q >> 2, c4 = q & 3;
            int row = row0 + r;
            float4 v = make_float4(0.f, 0.f, 0.f, 0.f);
            if (row < nrows) {
                float4 av = *(const float4*)&A[(long long)row * H_DIM + k0 + c4 * 4];
                float4 bv = *(const float4*)&b1[k0 + c4 * 4];
                v.x = fmaxf(av.x + bv.x, 0.f);
                v.y = fmaxf(av.y + bv.y, 0.f);
                v.z = fmaxf(av.z + bv.z, 0.f);
                v.w = fmaxf(av.w + bv.w, 0.f);
            }
            Xs[c4 * 4 + 0][r] = v.x;
            Xs[c4 * 4 + 1][r] = v.y;
            Xs[c4 * 4 + 2][r] = v.z;
            Xs[c4 * 4 + 3][r] = v.w;
        }
        {
            int r = t >> 4, c4 = t & 15;
            *(float4*)&Ws[r][c4 * 4] = *(const float4*)&W[(k0 + r) * C_DIM + c4 * 4];
        }
        __syncthreads();
#pragma unroll
        for (int k = 0; k < 16; ++k) {
            float4 a0 = *(const float4*)&Xs[k][ty * 8];
            float4 a1 = *(const float4*)&Xs[k][ty * 8 + 4];
            float4 b0 = *(const float4*)&Ws[k][tx * 4];
            float a[8] = {a0.x, a0.y, a0.z, a0.w, a1.x, a1.y, a1.z, a1.w};
            float b[4] = {b0.x, b0.y, b0.z, b0.w};
#pragma unroll
            for (int i = 0; i < 8; ++i)
#pragma unroll
                for (int j = 0; j < 4; ++j) acc[i][j] = fmaf(a[i], b[j], acc[i][j]);
        }
        __syncthreads();
    }
#pragma unroll
    for (int i = 0; i < 8; ++i) {
        int row = row0 + ty * 8 + i;
        if (row < nrows) {
            float4 c0 = make_float4(acc[i][0], acc[i][1], acc[i][2], acc[i][3]);
            *(float4*)&T[(long long)row * C_DIM + tx * 4] = c0;
        }
    }
}

// ---------------------------------------------------------------------------
// Gather aggregation: thread = (node, float4 chunk q); loops over in-edges.
// agg[n,:] = sum_{s in N(n)} t[s,:]*dis[s]*dis[n] + t[n,:]*dis[n]^2 (+ bias)
// ---------------------------------------------------------------------------
template <int SHIFT, bool HAS_BIAS>
__global__ __launch_bounds__(256) void agg_kernel(const float* __restrict__ t,
                                                  const float* __restrict__ dis,
                                                  const int* __restrict__ row_ptr,
                                                  const int* __restrict__ csr_src,
                                                  const float* __restrict__ bias,
                                                  float* __restrict__ agg) {
    unsigned idx = blockIdx.x * 256u + threadIdx.x;
    if (idx >= (unsigned)(N_NODES << SHIFT)) return;
    int node = idx >> SHIFT;
    int q = idx & ((1 << SHIFT) - 1);
    float dd = dis[node];
    int beg = row_ptr[node], end = row_ptr[node + 1];
    float4 v = ((const float4*)t)[idx];
    float c0 = dd * dd;
    float4 acc = make_float4(v.x * c0, v.y * c0, v.z * c0, v.w * c0);
    for (int j = beg; j < end; ++j) {
        int s = csr_src[j];
        float c = dis[s] * dd;
        float4 u = ((const float4*)t)[((unsigned)s << SHIFT) + q];
        acc.x = fmaf(u.x, c, acc.x);
        acc.y = fmaf(u.y, c, acc.y);
        acc.z = fmaf(u.z, c, acc.z);
        acc.w = fmaf(u.w, c, acc.w);
    }
    if (HAS_BIAS) {
        float4 bv = ((const float4*)bias)[q];
        acc.x += bv.x; acc.y += bv.y; acc.z += bv.z; acc.w += bv.w;
    }
    ((float4*)agg)[idx] = acc;
}

// ---------------------------------------------------------------------------
// Scoring: one wave (64 lanes) per test edge; dot over 64 features
// ---------------------------------------------------------------------------
__global__ __launch_bounds__(256) void score_kernel(const float* __restrict__ h2,
                                                    const int* __restrict__ pos,
                                                    const int* __restrict__ neg,
                                                    float* __restrict__ out) {
    int w = (blockIdx.x * 256 + threadIdx.x) >> 6;
    int lane = threadIdx.x & 63;
    if (w >= 2 * EP_EDGES) return;
    int i, j;
    if (w < EP_EDGES) {
        j = pos[w];
        i = pos[EP_EDGES + w];
    } else {
        j = neg[w - EP_EDGES];
        i = neg[w];
    }
    float v = h2[(long long)i * C_DIM + lane] * h2[(long long)j * C_DIM + lane];
#pragma unroll
    for (int o = 32; o > 0; o >>= 1) v += __shfl_down(v, o);
    if (lane == 0) out[w] = v;
}

// ---------------------------------------------------------------------------
extern "C" void kernel_launch(void* const* d_in, const int* in_sizes, int n_in,
                              void* d_out, int out_size, void* d_ws, size_t ws_size,
                              hipStream_t stream) {
    const float* x  = (const float*)d_in[0];
    const int* pos  = (const int*)d_in[2];
    const int* neg  = (const int*)d_in[3];
    const int* ei   = (const int*)d_in[4];
    const float* W1 = (const float*)d_in[5];
    const float* b1 = (const float*)d_in[6];
    const float* W2 = (const float*)d_in[7];
    const float* b2 = (const float*)d_in[8];
    float* out = (float*)d_out;

    char* ws = (char*)d_ws;
    float* dis    = (float*)(ws + 0);          //   400,000 B
    int*   row_ptr= (int*)  (ws + 400000);     //   400,004 B
    int*   csr_src= (int*)  (ws + 800128);     // 6,400,000 B
    float* t      = (float*)(ws + 7200128);    // 51,200,000 B
    float* agg    = (float*)(ws + 58400128);   // 51,200,000 B
    // scan scratch overlaid in agg region (consumed before agg is written):
    int* counts   = (int*)agg;                 // N ints
    int* cursor   = (int*)agg + 131072;        // N ints
    int* blocksum = (int*)agg + 262144;        // ~391 ints

    const int* esrc = ei;
    const int* edst = ei + E_EDGES;
    const int NB = (N_NODES + 255) / 256;      // 391

    // ---- CSR build (also produces dis) ----
    hipMemsetAsync(counts, 0, N_NODES * sizeof(int), stream);
    hist_kernel<<<E_EDGES / 256, 256, 0, stream>>>(edst, counts);
    dis_kernel<<<NB, 256, 0, stream>>>(counts, dis);
    scan1_kernel<<<NB, 256, 0, stream>>>(counts, row_ptr, blocksum);
    scan2_kernel<<<1, 512, 0, stream>>>(blocksum, NB);
    scan3_kernel<<<NB, 256, 0, stream>>>(counts, row_ptr, blocksum, cursor);
    fill_kernel<<<E_EDGES / 256, 256, 0, stream>>>(esrc, edst, cursor, csr_src);

    // ---- layer 1 ----
    gemm1_kernel<<<(N_NODES + 127) / 128, 256, 0, stream>>>(x, W1, t, N_NODES);
    agg_kernel<5, false><<<(N_NODES * 32) / 256, 256, 0, stream>>>(
        t, dis, row_ptr, csr_src, nullptr, agg);

    // ---- layer 2 (bias1+relu fused into gemm2's A-load; b2 fused into agg) ----
    gemm2_kernel<<<(N_NODES + 127) / 128, 256, 0, stream>>>(agg, b1, W2, t, N_NODES);
    agg_kernel<4, true><<<(N_NODES * 16) / 256, 256, 0, stream>>>(
        t, dis, row_ptr, csr_src, b2, agg);

    // ---- scoring ----
    score_kernel<<<(2 * EP_EDGES * 64) / 256, 256, 0, stream>>>(agg, pos, neg, out);

    // second output: zeros [2, 2*EP]
    hipMemsetAsync(out + 2 * EP_EDGES, 0, (size_t)4 * EP_EDGES * sizeof(float), stream);
}

// Round 3
// 711.429 us; speedup vs baseline: 6.3049x; 1.1710x over previous
//
#include <hip/hip_runtime.h>

#define N_NODES 100000
#define F_IN    256
#define H_DIM   128
#define C_DIM   64
#define E_EDGES 1600000
#define EP_EDGES 500000

// ---------------------------------------------------------------------------
// CSR build: histogram -> scan -> fill
// ---------------------------------------------------------------------------
__global__ __launch_bounds__(256) void hist_kernel(const int* __restrict__ dst,
                                                   int* __restrict__ counts) {
    int e = blockIdx.x * 256 + threadIdx.x;
    if (e < E_EDGES) atomicAdd(&counts[dst[e]], 1);
}

__global__ __launch_bounds__(256) void dis_kernel(const int* __restrict__ counts,
                                                  float* __restrict__ dis) {
    int i = blockIdx.x * 256 + threadIdx.x;
    if (i < N_NODES) dis[i] = rsqrtf((float)counts[i] + 1.0f);  // +1 self-loop
}

// per-block inclusive scan of counts -> row_ptr[i+1]; block totals -> blocksum
__global__ __launch_bounds__(256) void scan1_kernel(const int* __restrict__ counts,
                                                    int* __restrict__ row_ptr,
                                                    int* __restrict__ blocksum) {
    __shared__ int sh[256];
    int t = threadIdx.x;
    int i = blockIdx.x * 256 + t;
    int v = (i < N_NODES) ? counts[i] : 0;
    sh[t] = v;
    __syncthreads();
#pragma unroll
    for (int off = 1; off < 256; off <<= 1) {
        int u = (t >= off) ? sh[t - off] : 0;
        __syncthreads();
        sh[t] += u;
        __syncthreads();
    }
    if (i < N_NODES) row_ptr[i + 1] = sh[t];
    if (t == 255) blocksum[blockIdx.x] = sh[255];
}

// single-block exclusive scan of blocksum (nb <= 512)
__global__ __launch_bounds__(512) void scan2_kernel(int* __restrict__ blocksum, int nb) {
    __shared__ int sh[512];
    int t = threadIdx.x;
    sh[t] = (t < nb) ? blocksum[t] : 0;
    __syncthreads();
#pragma unroll
    for (int off = 1; off < 512; off <<= 1) {
        int u = (t >= off) ? sh[t - off] : 0;
        __syncthreads();
        sh[t] += u;
        __syncthreads();
    }
    if (t < nb) blocksum[t] = (t == 0) ? 0 : sh[t - 1];
}

// add block offsets; emit cursor[i] = exclusive prefix (fill start)
__global__ __launch_bounds__(256) void scan3_kernel(const int* __restrict__ counts,
                                                    int* __restrict__ row_ptr,
                                                    const int* __restrict__ blocksum,
                                                    int* __restrict__ cursor) {
    int i = blockIdx.x * 256 + threadIdx.x;
    if (i >= N_NODES) return;
    int incl = row_ptr[i + 1] + blocksum[blockIdx.x];
    row_ptr[i + 1] = incl;
    cursor[i] = incl - counts[i];
    if (i == 0) row_ptr[0] = 0;
}

__global__ __launch_bounds__(256) void fill_kernel(const int* __restrict__ src,
                                                   const int* __restrict__ dst,
                                                   int* __restrict__ cursor,
                                                   int* __restrict__ csr_src) {
    int e = blockIdx.x * 256 + threadIdx.x;
    if (e >= E_EDGES) return;
    int j = atomicAdd(&cursor[dst[e]], 1);
    csr_src[j] = src[e];
}

// ---------------------------------------------------------------------------
// GEMM1: T[N,128] = X[N,256] @ W1[256,128]   (fp32 vector ALU, tiled)
// ---------------------------------------------------------------------------
__global__ __launch_bounds__(256) void gemm1_kernel(const float* __restrict__ X,
                                                    const float* __restrict__ W,
                                                    float* __restrict__ T,
                                                    int nrows) {
    __shared__ float Xs[16][132];
    __shared__ float Ws[16][128];
    const int t = threadIdx.x;
    const int row0 = blockIdx.x * 128;
    const int ty = t >> 4;
    const int tx = t & 15;

    float acc[8][8];
#pragma unroll
    for (int i = 0; i < 8; ++i)
#pragma unroll
        for (int j = 0; j < 8; ++j) acc[i][j] = 0.0f;

    for (int k0 = 0; k0 < F_IN; k0 += 16) {
#pragma unroll
        for (int qi = 0; qi < 2; ++qi) {
            int q = t + qi * 256;
            int r = q >> 2, c4 = q & 3;
            int row = row0 + r;
            float4 v = make_float4(0.f, 0.f, 0.f, 0.f);
            if (row < nrows)
                v = *(const float4*)&X[(long long)row * F_IN + k0 + c4 * 4];
            Xs[c4 * 4 + 0][r] = v.x;
            Xs[c4 * 4 + 1][r] = v.y;
            Xs[c4 * 4 + 2][r] = v.z;
            Xs[c4 * 4 + 3][r] = v.w;
        }
#pragma unroll
        for (int qi = 0; qi < 2; ++qi) {
            int q = t + qi * 256;
            int r = q >> 5, c4 = q & 31;
            *(float4*)&Ws[r][c4 * 4] = *(const float4*)&W[(k0 + r) * H_DIM + c4 * 4];
        }
        __syncthreads();
#pragma unroll
        for (int k = 0; k < 16; ++k) {
            float4 a0 = *(const float4*)&Xs[k][ty * 8];
            float4 a1 = *(const float4*)&Xs[k][ty * 8 + 4];
            float4 b0 = *(const float4*)&Ws[k][tx * 4];
            float4 b1 = *(const float4*)&Ws[k][tx * 4 + 64];
            float a[8] = {a0.x, a0.y, a0.z, a0.w, a1.x, a1.y, a1.z, a1.w};
            float b[8] = {b0.x, b0.y, b0.z, b0.w, b1.x, b1.y, b1.z, b1.w};
#pragma unroll
            for (int i = 0; i < 8; ++i)
#pragma unroll
                for (int j = 0; j < 8; ++j) acc[i][j] = fmaf(a[i], b[j], acc[i][j]);
        }
        __syncthreads();
    }
#pragma unroll
    for (int i = 0; i < 8; ++i) {
        int row = row0 + ty * 8 + i;
        if (row < nrows) {
            float4 c0 = make_float4(acc[i][0], acc[i][1], acc[i][2], acc[i][3]);
            float4 c1 = make_float4(acc[i][4], acc[i][5], acc[i][6], acc[i][7]);
            *(float4*)&T[(long long)row * H_DIM + tx * 4] = c0;
            *(float4*)&T[(long long)row * H_DIM + 64 + tx * 4] = c1;
        }
    }
}

// ---------------------------------------------------------------------------
// GEMM2: T2[N,64] = relu(AGG1[N,128] + b1) @ W2[128,64]
// ---------------------------------------------------------------------------
__global__ __launch_bounds__(256) void gemm2_kernel(const float* __restrict__ A,
                                                    const float* __restrict__ b1,
                                                    const float* __restrict__ W,
                                                    float* __restrict__ T,
                                                    int nrows) {
    __shared__ float Xs[16][132];
    __shared__ float Ws[16][64];
    const int t = threadIdx.x;
    const int row0 = blockIdx.x * 128;
    const int ty = t >> 4;
    const int tx = t & 15;

    float acc[8][4];
#pragma unroll
    for (int i = 0; i < 8; ++i)
#pragma unroll
        for (int j = 0; j < 4; ++j) acc[i][j] = 0.0f;

    for (int k0 = 0; k0 < H_DIM; k0 += 16) {
#pragma unroll
        for (int qi = 0; qi < 2; ++qi) {
            int q = t + qi * 256;
            int r = q >> 2, c4 = q & 3;
            int row = row0 + r;
            float4 v = make_float4(0.f, 0.f, 0.f, 0.f);
            if (row < nrows) {
                float4 av = *(const float4*)&A[(long long)row * H_DIM + k0 + c4 * 4];
                float4 bv = *(const float4*)&b1[k0 + c4 * 4];
                v.x = fmaxf(av.x + bv.x, 0.f);
                v.y = fmaxf(av.y + bv.y, 0.f);
                v.z = fmaxf(av.z + bv.z, 0.f);
                v.w = fmaxf(av.w + bv.w, 0.f);
            }
            Xs[c4 * 4 + 0][r] = v.x;
            Xs[c4 * 4 + 1][r] = v.y;
            Xs[c4 * 4 + 2][r] = v.z;
            Xs[c4 * 4 + 3][r] = v.w;
        }
        {
            int r = t >> 4, c4 = t & 15;
            *(float4*)&Ws[r][c4 * 4] = *(const float4*)&W[(k0 + r) * C_DIM + c4 * 4];
        }
        __syncthreads();
#pragma unroll
        for (int k = 0; k < 16; ++k) {
            float4 a0 = *(const float4*)&Xs[k][ty * 8];
            float4 a1 = *(const float4*)&Xs[k][ty * 8 + 4];
            float4 b0 = *(const float4*)&Ws[k][tx * 4];
            float a[8] = {a0.x, a0.y, a0.z, a0.w, a1.x, a1.y, a1.z, a1.w};
            float b[4] = {b0.x, b0.y, b0.z, b0.w};
#pragma unroll
            for (int i = 0; i < 8; ++i)
#pragma unroll
                for (int j = 0; j < 4; ++j) acc[i][j] = fmaf(a[i], b[j], acc[i][j]);
        }
        __syncthreads();
    }
#pragma unroll
    for (int i = 0; i < 8; ++i) {
        int row = row0 + ty * 8 + i;
        if (row < nrows) {
            float4 c0 = make_float4(acc[i][0], acc[i][1], acc[i][2], acc[i][3]);
            *(float4*)&T[(long long)row * C_DIM + tx * 4] = c0;
        }
    }
}

// ---------------------------------------------------------------------------
// Gather aggregation: thread = (node, float4 chunk q); loops over in-edges.
// agg[n,:] = sum_{s in N(n)} t[s,:]*dis[s]*dis[n] + t[n,:]*dis[n]^2 (+ bias)
// ---------------------------------------------------------------------------
template <int SHIFT, bool HAS_BIAS>
__global__ __launch_bounds__(256) void agg_kernel(const float* __restrict__ t,
                                                  const float* __restrict__ dis,
                                                  const int* __restrict__ row_ptr,
                                                  const int* __restrict__ csr_src,
                                                  const float* __restrict__ bias,
                                                  float* __restrict__ agg) {
    unsigned idx = blockIdx.x * 256u + threadIdx.x;
    if (idx >= (unsigned)(N_NODES << SHIFT)) return;
    int node = idx >> SHIFT;
    int q = idx & ((1 << SHIFT) - 1);
    float dd = dis[node];
    int beg = row_ptr[node], end = row_ptr[node + 1];
    float4 v = ((const float4*)t)[idx];
    float c0 = dd * dd;
    float4 acc = make_float4(v.x * c0, v.y * c0, v.z * c0, v.w * c0);
    for (int j = beg; j < end; ++j) {
        int s = csr_src[j];
        float c = dis[s] * dd;
        float4 u = ((const float4*)t)[((unsigned)s << SHIFT) + q];
        acc.x = fmaf(u.x, c, acc.x);
        acc.y = fmaf(u.y, c, acc.y);
        acc.z = fmaf(u.z, c, acc.z);
        acc.w = fmaf(u.w, c, acc.w);
    }
    if (HAS_BIAS) {
        float4 bv = ((const float4*)bias)[q];
        acc.x += bv.x; acc.y += bv.y; acc.z += bv.z; acc.w += bv.w;
    }
    ((float4*)agg)[idx] = acc;
}

// ---------------------------------------------------------------------------
// Scoring: 16 lanes per test edge (4 edges/wave); float4 loads, width-16 reduce
// ---------------------------------------------------------------------------
__global__ __launch_bounds__(256) void score_kernel(const float* __restrict__ h2,
                                                    const int* __restrict__ pos,
                                                    const int* __restrict__ neg,
                                                    float* __restrict__ out) {
    int tid = blockIdx.x * 256 + threadIdx.x;
    int e = tid >> 4;       // edge id
    int q = tid & 15;       // float4 chunk within 64-feature row
    if (e >= 2 * EP_EDGES) return;
    int i, j;
    if (e < EP_EDGES) {
        j = pos[e];              // tei[0] (src)
        i = pos[EP_EDGES + e];   // tei[1] (dst)
    } else {
        j = neg[e - EP_EDGES];
        i = neg[e];
    }
    float4 a = ((const float4*)h2)[i * (C_DIM / 4) + q];
    float4 b = ((const float4*)h2)[j * (C_DIM / 4) + q];
    float v = a.x * b.x + a.y * b.y + a.z * b.z + a.w * b.w;
    v += __shfl_down(v, 8, 16);
    v += __shfl_down(v, 4, 16);
    v += __shfl_down(v, 2, 16);
    v += __shfl_down(v, 1, 16);
    if (q == 0) out[e] = v;
}

// ---------------------------------------------------------------------------
extern "C" void kernel_launch(void* const* d_in, const int* in_sizes, int n_in,
                              void* d_out, int out_size, void* d_ws, size_t ws_size,
                              hipStream_t stream) {
    const float* x  = (const float*)d_in[0];
    const int* pos  = (const int*)d_in[2];
    const int* neg  = (const int*)d_in[3];
    const int* ei   = (const int*)d_in[4];
    const float* W1 = (const float*)d_in[5];
    const float* b1 = (const float*)d_in[6];
    const float* W2 = (const float*)d_in[7];
    const float* b2 = (const float*)d_in[8];
    float* out = (float*)d_out;

    char* ws = (char*)d_ws;
    float* dis    = (float*)(ws + 0);          //   400,000 B
    int*   row_ptr= (int*)  (ws + 400000);     //   400,004 B
    int*   csr_src= (int*)  (ws + 800128);     // 6,400,000 B
    float* t      = (float*)(ws + 7200128);    // 51,200,000 B
    float* agg    = (float*)(ws + 58400128);   // 51,200,000 B
    // scan scratch overlaid in agg region (consumed before agg is written):
    int* counts   = (int*)agg;                 // N ints
    int* cursor   = (int*)agg + 131072;        // N ints
    int* blocksum = (int*)agg + 262144;        // ~391 ints

    const int* esrc = ei;
    const int* edst = ei + E_EDGES;
    const int NB = (N_NODES + 255) / 256;      // 391

    // ---- CSR build (also produces dis) ----
    hipMemsetAsync(counts, 0, N_NODES * sizeof(int), stream);
    hist_kernel<<<E_EDGES / 256, 256, 0, stream>>>(edst, counts);
    dis_kernel<<<NB, 256, 0, stream>>>(counts, dis);
    scan1_kernel<<<NB, 256, 0, stream>>>(counts, row_ptr, blocksum);
    scan2_kernel<<<1, 512, 0, stream>>>(blocksum, NB);
    scan3_kernel<<<NB, 256, 0, stream>>>(counts, row_ptr, blocksum, cursor);
    fill_kernel<<<E_EDGES / 256, 256, 0, stream>>>(esrc, edst, cursor, csr_src);

    // ---- layer 1 ----
    gemm1_kernel<<<(N_NODES + 127) / 128, 256, 0, stream>>>(x, W1, t, N_NODES);
    agg_kernel<5, false><<<(N_NODES * 32) / 256, 256, 0, stream>>>(
        t, dis, row_ptr, csr_src, nullptr, agg);

    // ---- layer 2 (bias1+relu fused into gemm2's A-load; b2 fused into agg) ----
    gemm2_kernel<<<(N_NODES + 127) / 128, 256, 0, stream>>>(agg, b1, W2, t, N_NODES);
    agg_kernel<4, true><<<(N_NODES * 16) / 256, 256, 0, stream>>>(
        t, dis, row_ptr, csr_src, b2, agg);

    // ---- scoring (16 lanes/edge) ----
    score_kernel<<<(2 * EP_EDGES * 16) / 256, 256, 0, stream>>>(agg, pos, neg, out);

    // second output: zeros [2, 2*EP]
    hipMemsetAsync(out + 2 * EP_EDGES, 0, (size_t)4 * EP_EDGES * sizeof(float), stream);
}

// Round 4
// 634.786 us; speedup vs baseline: 7.0662x; 1.1207x over previous
//
#include <hip/hip_runtime.h>

#define N_NODES 100000
#define F_IN    256
#define H_DIM   128
#define C_DIM   64
#define E_EDGES 1600000
#define EP_EDGES 500000

typedef unsigned short bf16_t;

__device__ inline bf16_t f2bf(float f) {          // round-to-nearest-even
    unsigned u = __float_as_uint(f);
    u += 0x7fff + ((u >> 16) & 1);
    return (bf16_t)(u >> 16);
}

// ---------------------------------------------------------------------------
// CSR build: histogram -> scan -> fill
// ---------------------------------------------------------------------------
__global__ __launch_bounds__(256) void hist_kernel(const int* __restrict__ dst,
                                                   int* __restrict__ counts) {
    int e = blockIdx.x * 256 + threadIdx.x;
    if (e < E_EDGES) atomicAdd(&counts[dst[e]], 1);
}

__global__ __launch_bounds__(256) void dis_kernel(const int* __restrict__ counts,
                                                  float* __restrict__ dis) {
    int i = blockIdx.x * 256 + threadIdx.x;
    if (i < N_NODES) dis[i] = rsqrtf((float)counts[i] + 1.0f);  // +1 self-loop
}

__global__ __launch_bounds__(256) void scan1_kernel(const int* __restrict__ counts,
                                                    int* __restrict__ row_ptr,
                                                    int* __restrict__ blocksum) {
    __shared__ int sh[256];
    int t = threadIdx.x;
    int i = blockIdx.x * 256 + t;
    int v = (i < N_NODES) ? counts[i] : 0;
    sh[t] = v;
    __syncthreads();
#pragma unroll
    for (int off = 1; off < 256; off <<= 1) {
        int u = (t >= off) ? sh[t - off] : 0;
        __syncthreads();
        sh[t] += u;
        __syncthreads();
    }
    if (i < N_NODES) row_ptr[i + 1] = sh[t];
    if (t == 255) blocksum[blockIdx.x] = sh[255];
}

__global__ __launch_bounds__(512) void scan2_kernel(int* __restrict__ blocksum, int nb) {
    __shared__ int sh[512];
    int t = threadIdx.x;
    sh[t] = (t < nb) ? blocksum[t] : 0;
    __syncthreads();
#pragma unroll
    for (int off = 1; off < 512; off <<= 1) {
        int u = (t >= off) ? sh[t - off] : 0;
        __syncthreads();
        sh[t] += u;
        __syncthreads();
    }
    if (t < nb) blocksum[t] = (t == 0) ? 0 : sh[t - 1];
}

__global__ __launch_bounds__(256) void scan3_kernel(const int* __restrict__ counts,
                                                    int* __restrict__ row_ptr,
                                                    const int* __restrict__ blocksum,
                                                    int* __restrict__ cursor) {
    int i = blockIdx.x * 256 + threadIdx.x;
    if (i >= N_NODES) return;
    int incl = row_ptr[i + 1] + blocksum[blockIdx.x];
    row_ptr[i + 1] = incl;
    cursor[i] = incl - counts[i];
    if (i == 0) row_ptr[0] = 0;
}

__global__ __launch_bounds__(256) void fill_kernel(const int* __restrict__ src,
                                                   const int* __restrict__ dst,
                                                   int* __restrict__ cursor,
                                                   int* __restrict__ csr_src) {
    int e = blockIdx.x * 256 + threadIdx.x;
    if (e >= E_EDGES) return;
    int j = atomicAdd(&cursor[dst[e]], 1);
    csr_src[j] = src[e];
}

// ---------------------------------------------------------------------------
// GEMM1: T[N,128] = X[N,256] @ W1[256,128]  -> bf16 output
// ---------------------------------------------------------------------------
__global__ __launch_bounds__(256) void gemm1_kernel(const float* __restrict__ X,
                                                    const float* __restrict__ W,
                                                    bf16_t* __restrict__ T,
                                                    int nrows) {
    __shared__ float Xs[16][132];
    __shared__ float Ws[16][128];
    const int t = threadIdx.x;
    const int row0 = blockIdx.x * 128;
    const int ty = t >> 4;
    const int tx = t & 15;

    float acc[8][8];
#pragma unroll
    for (int i = 0; i < 8; ++i)
#pragma unroll
        for (int j = 0; j < 8; ++j) acc[i][j] = 0.0f;

    for (int k0 = 0; k0 < F_IN; k0 += 16) {
#pragma unroll
        for (int qi = 0; qi < 2; ++qi) {
            int q = t + qi * 256;
            int r = q >> 2, c4 = q & 3;
            int row = row0 + r;
            float4 v = make_float4(0.f, 0.f, 0.f, 0.f);
            if (row < nrows)
                v = *(const float4*)&X[(long long)row * F_IN + k0 + c4 * 4];
            Xs[c4 * 4 + 0][r] = v.x;
            Xs[c4 * 4 + 1][r] = v.y;
            Xs[c4 * 4 + 2][r] = v.z;
            Xs[c4 * 4 + 3][r] = v.w;
        }
#pragma unroll
        for (int qi = 0; qi < 2; ++qi) {
            int q = t + qi * 256;
            int r = q >> 5, c4 = q & 31;
            *(float4*)&Ws[r][c4 * 4] = *(const float4*)&W[(k0 + r) * H_DIM + c4 * 4];
        }
        __syncthreads();
#pragma unroll
        for (int k = 0; k < 16; ++k) {
            float4 a0 = *(const float4*)&Xs[k][ty * 8];
            float4 a1 = *(const float4*)&Xs[k][ty * 8 + 4];
            float4 b0 = *(const float4*)&Ws[k][tx * 4];
            float4 b1 = *(const float4*)&Ws[k][tx * 4 + 64];
            float a[8] = {a0.x, a0.y, a0.z, a0.w, a1.x, a1.y, a1.z, a1.w};
            float b[8] = {b0.x, b0.y, b0.z, b0.w, b1.x, b1.y, b1.z, b1.w};
#pragma unroll
            for (int i = 0; i < 8; ++i)
#pragma unroll
                for (int j = 0; j < 8; ++j) acc[i][j] = fmaf(a[i], b[j], acc[i][j]);
        }
        __syncthreads();
    }
#pragma unroll
    for (int i = 0; i < 8; ++i) {
        int row = row0 + ty * 8 + i;
        if (row < nrows) {
            ushort4 c0, c1;
            c0.x = f2bf(acc[i][0]); c0.y = f2bf(acc[i][1]);
            c0.z = f2bf(acc[i][2]); c0.w = f2bf(acc[i][3]);
            c1.x = f2bf(acc[i][4]); c1.y = f2bf(acc[i][5]);
            c1.z = f2bf(acc[i][6]); c1.w = f2bf(acc[i][7]);
            *(ushort4*)&T[(long long)row * H_DIM + tx * 4] = c0;
            *(ushort4*)&T[(long long)row * H_DIM + 64 + tx * 4] = c1;
        }
    }
}

// ---------------------------------------------------------------------------
// GEMM2: T2[N,64] = relu(AGG1[N,128] + b1) @ W2[128,64] -> bf16 output
// ---------------------------------------------------------------------------
__global__ __launch_bounds__(256) void gemm2_kernel(const float* __restrict__ A,
                                                    const float* __restrict__ b1,
                                                    const float* __restrict__ W,
                                                    bf16_t* __restrict__ T,
                                                    int nrows) {
    __shared__ float Xs[16][132];
    __shared__ float Ws[16][64];
    const int t = threadIdx.x;
    const int row0 = blockIdx.x * 128;
    const int ty = t >> 4;
    const int tx = t & 15;

    float acc[8][4];
#pragma unroll
    for (int i = 0; i < 8; ++i)
#pragma unroll
        for (int j = 0; j < 4; ++j) acc[i][j] = 0.0f;

    for (int k0 = 0; k0 < H_DIM; k0 += 16) {
#pragma unroll
        for (int qi = 0; qi < 2; ++qi) {
            int q = t + qi * 256;
            int r = q >> 2, c4 = q & 3;
            int row = row0 + r;
            float4 v = make_float4(0.f, 0.f, 0.f, 0.f);
            if (row < nrows) {
                float4 av = *(const float4*)&A[(long long)row * H_DIM + k0 + c4 * 4];
                float4 bv = *(const float4*)&b1[k0 + c4 * 4];
                v.x = fmaxf(av.x + bv.x, 0.f);
                v.y = fmaxf(av.y + bv.y, 0.f);
                v.z = fmaxf(av.z + bv.z, 0.f);
                v.w = fmaxf(av.w + bv.w, 0.f);
            }
            Xs[c4 * 4 + 0][r] = v.x;
            Xs[c4 * 4 + 1][r] = v.y;
            Xs[c4 * 4 + 2][r] = v.z;
            Xs[c4 * 4 + 3][r] = v.w;
        }
        {
            int r = t >> 4, c4 = t & 15;
            *(float4*)&Ws[r][c4 * 4] = *(const float4*)&W[(k0 + r) * C_DIM + c4 * 4];
        }
        __syncthreads();
#pragma unroll
        for (int k = 0; k < 16; ++k) {
            float4 a0 = *(const float4*)&Xs[k][ty * 8];
            float4 a1 = *(const float4*)&Xs[k][ty * 8 + 4];
            float4 b0 = *(const float4*)&Ws[k][tx * 4];
            float a[8] = {a0.x, a0.y, a0.z, a0.w, a1.x, a1.y, a1.z, a1.w};
            float b[4] = {b0.x, b0.y, b0.z, b0.w};
#pragma unroll
            for (int i = 0; i < 8; ++i)
#pragma unroll
                for (int j = 0; j < 4; ++j) acc[i][j] = fmaf(a[i], b[j], acc[i][j]);
        }
        __syncthreads();
    }
#pragma unroll
    for (int i = 0; i < 8; ++i) {
        int row = row0 + ty * 8 + i;
        if (row < nrows) {
            ushort4 c0;
            c0.x = f2bf(acc[i][0]); c0.y = f2bf(acc[i][1]);
            c0.z = f2bf(acc[i][2]); c0.w = f2bf(acc[i][3]);
            *(ushort4*)&T[(long long)row * C_DIM + tx * 4] = c0;
        }
    }
}

// ---------------------------------------------------------------------------
// Gather aggregation over bf16 t: thread = (node, 8-elem chunk q).
// agg[n,:] = sum_{s in N(n)} t[s,:]*dis[s]*dis[n] + t[n,:]*dis[n]^2 (+ bias)
// CS = log2(chunks per row); row = (1<<CS)*8 elements.
// ---------------------------------------------------------------------------
__device__ inline void fma8_bf16(float* acc, uint4 u, float c) {
#pragma unroll
    for (int p = 0; p < 4; ++p) {
        unsigned w = (&u.x)[p];
        float lo = __uint_as_float(w << 16);
        float hi = __uint_as_float(w & 0xffff0000u);
        acc[2 * p]     = fmaf(lo, c, acc[2 * p]);
        acc[2 * p + 1] = fmaf(hi, c, acc[2 * p + 1]);
    }
}

template <int CS, bool HAS_BIAS>
__global__ __launch_bounds__(256) void agg_kernel(const bf16_t* __restrict__ t,
                                                  const float* __restrict__ dis,
                                                  const int* __restrict__ row_ptr,
                                                  const int* __restrict__ csr_src,
                                                  const float* __restrict__ bias,
                                                  float* __restrict__ agg) {
    unsigned idx = blockIdx.x * 256u + threadIdx.x;
    if (idx >= (unsigned)(N_NODES << CS)) return;
    int node = idx >> CS;
    int q = idx & ((1 << CS) - 1);
    const uint4* tv = (const uint4*)t;
    float dd = dis[node];
    int beg = row_ptr[node], end = row_ptr[node + 1];

    float acc[8];
#pragma unroll
    for (int p = 0; p < 8; ++p) acc[p] = 0.0f;
    fma8_bf16(acc, tv[idx], dd * dd);  // self-loop term

    int j = beg;
    for (; j + 3 < end; j += 4) {
        int s0 = csr_src[j + 0], s1 = csr_src[j + 1];
        int s2 = csr_src[j + 2], s3 = csr_src[j + 3];
        float c0 = dis[s0] * dd, c1 = dis[s1] * dd;
        float c2 = dis[s2] * dd, c3 = dis[s3] * dd;
        uint4 u0 = tv[((unsigned)s0 << CS) + q];
        uint4 u1 = tv[((unsigned)s1 << CS) + q];
        uint4 u2 = tv[((unsigned)s2 << CS) + q];
        uint4 u3 = tv[((unsigned)s3 << CS) + q];
        fma8_bf16(acc, u0, c0);
        fma8_bf16(acc, u1, c1);
        fma8_bf16(acc, u2, c2);
        fma8_bf16(acc, u3, c3);
    }
    for (; j < end; ++j) {
        int s = csr_src[j];
        float c = dis[s] * dd;
        fma8_bf16(acc, tv[((unsigned)s << CS) + q], c);
    }

    if (HAS_BIAS) {
        float4 bv0 = ((const float4*)bias)[q * 2];
        float4 bv1 = ((const float4*)bias)[q * 2 + 1];
        acc[0] += bv0.x; acc[1] += bv0.y; acc[2] += bv0.z; acc[3] += bv0.w;
        acc[4] += bv1.x; acc[5] += bv1.y; acc[6] += bv1.z; acc[7] += bv1.w;
    }
    float4 o0 = make_float4(acc[0], acc[1], acc[2], acc[3]);
    float4 o1 = make_float4(acc[4], acc[5], acc[6], acc[7]);
    ((float4*)agg)[idx * 2]     = o0;
    ((float4*)agg)[idx * 2 + 1] = o1;
}

// ---------------------------------------------------------------------------
// Scoring: 16 lanes per test edge (4 edges/wave); float4 loads, width-16 reduce
// ---------------------------------------------------------------------------
__global__ __launch_bounds__(256) void score_kernel(const float* __restrict__ h2,
                                                    const int* __restrict__ pos,
                                                    const int* __restrict__ neg,
                                                    float* __restrict__ out) {
    int tid = blockIdx.x * 256 + threadIdx.x;
    int e = tid >> 4;
    int q = tid & 15;
    if (e >= 2 * EP_EDGES) return;
    int i, j;
    if (e < EP_EDGES) {
        j = pos[e];
        i = pos[EP_EDGES + e];
    } else {
        j = neg[e - EP_EDGES];
        i = neg[e];
    }
    float4 a = ((const float4*)h2)[i * (C_DIM / 4) + q];
    float4 b = ((const float4*)h2)[j * (C_DIM / 4) + q];
    float v = a.x * b.x + a.y * b.y + a.z * b.z + a.w * b.w;
    v += __shfl_down(v, 8, 16);
    v += __shfl_down(v, 4, 16);
    v += __shfl_down(v, 2, 16);
    v += __shfl_down(v, 1, 16);
    if (q == 0) out[e] = v;
}

// ---------------------------------------------------------------------------
extern "C" void kernel_launch(void* const* d_in, const int* in_sizes, int n_in,
                              void* d_out, int out_size, void* d_ws, size_t ws_size,
                              hipStream_t stream) {
    const float* x  = (const float*)d_in[0];
    const int* pos  = (const int*)d_in[2];
    const int* neg  = (const int*)d_in[3];
    const int* ei   = (const int*)d_in[4];
    const float* W1 = (const float*)d_in[5];
    const float* b1 = (const float*)d_in[6];
    const float* W2 = (const float*)d_in[7];
    const float* b2 = (const float*)d_in[8];
    float* out = (float*)d_out;

    char* ws = (char*)d_ws;
    float*  dis    = (float*) (ws + 0);          //   400,000 B
    int*    row_ptr= (int*)   (ws + 400000);     //   400,004 B
    int*    csr_src= (int*)   (ws + 800128);     // 6,400,000 B
    bf16_t* t      = (bf16_t*)(ws + 7200128);    // 25,600,000 B (N*128 bf16)
    float*  agg    = (float*) (ws + 32800128);   // 51,200,000 B (N*128 fp32)
    // scan scratch overlaid in agg region (consumed before agg is written):
    int* counts   = (int*)agg;
    int* cursor   = (int*)agg + 131072;
    int* blocksum = (int*)agg + 262144;

    const int* esrc = ei;
    const int* edst = ei + E_EDGES;
    const int NB = (N_NODES + 255) / 256;      // 391

    // ---- CSR build (also produces dis) ----
    hipMemsetAsync(counts, 0, N_NODES * sizeof(int), stream);
    hist_kernel<<<E_EDGES / 256, 256, 0, stream>>>(edst, counts);
    dis_kernel<<<NB, 256, 0, stream>>>(counts, dis);
    scan1_kernel<<<NB, 256, 0, stream>>>(counts, row_ptr, blocksum);
    scan2_kernel<<<1, 512, 0, stream>>>(blocksum, NB);
    scan3_kernel<<<NB, 256, 0, stream>>>(counts, row_ptr, blocksum, cursor);
    fill_kernel<<<E_EDGES / 256, 256, 0, stream>>>(esrc, edst, cursor, csr_src);

    // ---- layer 1 ----
    gemm1_kernel<<<(N_NODES + 127) / 128, 256, 0, stream>>>(x, W1, t, N_NODES);
    agg_kernel<4, false><<<(N_NODES * 16 + 255) / 256, 256, 0, stream>>>(
        t, dis, row_ptr, csr_src, nullptr, agg);

    // ---- layer 2 ----
    gemm2_kernel<<<(N_NODES + 127) / 128, 256, 0, stream>>>(agg, b1, W2, t, N_NODES);
    agg_kernel<3, true><<<(N_NODES * 8 + 255) / 256, 256, 0, stream>>>(
        t, dis, row_ptr, csr_src, b2, agg);

    // ---- scoring (16 lanes/edge) ----
    score_kernel<<<(2 * EP_EDGES * 16) / 256, 256, 0, stream>>>(agg, pos, neg, out);

    // second output: zeros [2, 2*EP]
    hipMemsetAsync(out + 2 * EP_EDGES, 0, (size_t)4 * EP_EDGES * sizeof(float), stream);
}

// Round 5
// 539.134 us; speedup vs baseline: 8.3198x; 1.1774x over previous
//
#include <hip/hip_runtime.h>

#define N_NODES 100000
#define F_IN    256
#define H_DIM   128
#define C_DIM   64
#define E_EDGES 1600000
#define EP_EDGES 500000

#define NBUK 391          // buckets of 256 nodes: bucket = dst >> 8
#define EPB  4096         // edges per bucket_scatter block

typedef unsigned short bf16_t;

__device__ inline bf16_t f2bf(float f) {          // round-to-nearest-even
    unsigned u = __float_as_uint(f);
    u += 0x7fff + ((u >> 16) & 1);
    return (bf16_t)(u >> 16);
}

// ---------------------------------------------------------------------------
// CSR build: histogram -> scan -> bucket scatter -> bucket sort
// ---------------------------------------------------------------------------
__global__ __launch_bounds__(256) void hist_kernel(const int* __restrict__ dst,
                                                   int* __restrict__ counts) {
    int e = blockIdx.x * 256 + threadIdx.x;
    if (e < E_EDGES) atomicAdd(&counts[dst[e]], 1);
}

__global__ __launch_bounds__(256) void dis_kernel(const int* __restrict__ counts,
                                                  float* __restrict__ dis) {
    int i = blockIdx.x * 256 + threadIdx.x;
    if (i < N_NODES) dis[i] = rsqrtf((float)counts[i] + 1.0f);  // +1 self-loop
}

__global__ __launch_bounds__(256) void scan1_kernel(const int* __restrict__ counts,
                                                    int* __restrict__ row_ptr,
                                                    int* __restrict__ blocksum) {
    __shared__ int sh[256];
    int t = threadIdx.x;
    int i = blockIdx.x * 256 + t;
    int v = (i < N_NODES) ? counts[i] : 0;
    sh[t] = v;
    __syncthreads();
#pragma unroll
    for (int off = 1; off < 256; off <<= 1) {
        int u = (t >= off) ? sh[t - off] : 0;
        __syncthreads();
        sh[t] += u;
        __syncthreads();
    }
    if (i < N_NODES) row_ptr[i + 1] = sh[t];
    if (t == 255) blocksum[blockIdx.x] = sh[255];
}

__global__ __launch_bounds__(512) void scan2_kernel(int* __restrict__ blocksum, int nb) {
    __shared__ int sh[512];
    int t = threadIdx.x;
    sh[t] = (t < nb) ? blocksum[t] : 0;
    __syncthreads();
#pragma unroll
    for (int off = 1; off < 512; off <<= 1) {
        int u = (t >= off) ? sh[t - off] : 0;
        __syncthreads();
        sh[t] += u;
        __syncthreads();
    }
    if (t < nb) blocksum[t] = (t == 0) ? 0 : sh[t - 1];
}

__global__ __launch_bounds__(256) void scan3_kernel(int* __restrict__ row_ptr,
                                                    const int* __restrict__ blocksum) {
    int i = blockIdx.x * 256 + threadIdx.x;
    if (i >= N_NODES) return;
    row_ptr[i + 1] += blocksum[blockIdx.x];
    if (i == 0) row_ptr[0] = 0;
}

__global__ __launch_bounds__(512) void binit_kernel(const int* __restrict__ row_ptr,
                                                    int* __restrict__ bcursor) {
    int b = threadIdx.x;
    if (b < NBUK) bcursor[b] = row_ptr[b << 8];
}

// Bin edges into 256-node buckets; per-block chunk claims keep writes line-dense.
__global__ __launch_bounds__(256) void bucket_scatter_kernel(const int* __restrict__ src,
                                                             const int* __restrict__ dst,
                                                             int* __restrict__ bcursor,
                                                             int2* __restrict__ pairs) {
    __shared__ int hist[NBUK];
    __shared__ int base[NBUK];
    const int t = threadIdx.x;
    for (int b = t; b < NBUK; b += 256) hist[b] = 0;
    __syncthreads();

    const int e0 = blockIdx.x * EPB;
    int s[16], d[16];
#pragma unroll
    for (int i = 0; i < 16; ++i) {
        int e = e0 + i * 256 + t;
        if (e < E_EDGES) {
            s[i] = src[e];
            d[i] = dst[e];
            atomicAdd(&hist[d[i] >> 8], 1);
        } else {
            d[i] = -1;
        }
    }
    __syncthreads();
    for (int b = t; b < NBUK; b += 256) {
        int c = hist[b];
        base[b] = c ? atomicAdd(&bcursor[b], c) : 0;
        hist[b] = 0;  // reuse as rank counter
    }
    __syncthreads();
#pragma unroll
    for (int i = 0; i < 16; ++i) {
        if (d[i] >= 0) {
            int b = d[i] >> 8;
            int r = atomicAdd(&hist[b], 1);
            pairs[base[b] + r] = make_int2(s[i], d[i]);
        }
    }
}

// One block per bucket: counting-sort the bucket's pairs by node into csr_src.
// The block is the only writer of its contiguous csr_src region.
__global__ __launch_bounds__(256) void bucket_sort_kernel(const int2* __restrict__ pairs,
                                                          const int* __restrict__ row_ptr,
                                                          int* __restrict__ csr_src) {
    __shared__ int cursor[256];
    const int b = blockIdx.x;
    const int node0 = b << 8;
    const int t = threadIdx.x;
    const int nn = min(256, N_NODES - node0);
    if (t < nn) cursor[t] = row_ptr[node0 + t];
    __syncthreads();
    const int beg = row_ptr[node0];
    const int end = row_ptr[node0 + nn];
    for (int e = beg + t; e < end; e += 256) {
        int2 p = pairs[e];
        int j = atomicAdd(&cursor[p.y - node0], 1);
        csr_src[j] = p.x;
    }
}

// ---------------------------------------------------------------------------
// GEMM1: T[N,128] = X[N,256] @ W1[256,128]  -> bf16 output
// ---------------------------------------------------------------------------
__global__ __launch_bounds__(256) void gemm1_kernel(const float* __restrict__ X,
                                                    const float* __restrict__ W,
                                                    bf16_t* __restrict__ T,
                                                    int nrows) {
    __shared__ float Xs[16][132];
    __shared__ float Ws[16][128];
    const int t = threadIdx.x;
    const int row0 = blockIdx.x * 128;
    const int ty = t >> 4;
    const int tx = t & 15;

    float acc[8][8];
#pragma unroll
    for (int i = 0; i < 8; ++i)
#pragma unroll
        for (int j = 0; j < 8; ++j) acc[i][j] = 0.0f;

    for (int k0 = 0; k0 < F_IN; k0 += 16) {
#pragma unroll
        for (int qi = 0; qi < 2; ++qi) {
            int q = t + qi * 256;
            int r = q >> 2, c4 = q & 3;
            int row = row0 + r;
            float4 v = make_float4(0.f, 0.f, 0.f, 0.f);
            if (row < nrows)
                v = *(const float4*)&X[(long long)row * F_IN + k0 + c4 * 4];
            Xs[c4 * 4 + 0][r] = v.x;
            Xs[c4 * 4 + 1][r] = v.y;
            Xs[c4 * 4 + 2][r] = v.z;
            Xs[c4 * 4 + 3][r] = v.w;
        }
#pragma unroll
        for (int qi = 0; qi < 2; ++qi) {
            int q = t + qi * 256;
            int r = q >> 5, c4 = q & 31;
            *(float4*)&Ws[r][c4 * 4] = *(const float4*)&W[(k0 + r) * H_DIM + c4 * 4];
        }
        __syncthreads();
#pragma unroll
        for (int k = 0; k < 16; ++k) {
            float4 a0 = *(const float4*)&Xs[k][ty * 8];
            float4 a1 = *(const float4*)&Xs[k][ty * 8 + 4];
            float4 b0 = *(const float4*)&Ws[k][tx * 4];
            float4 b1 = *(const float4*)&Ws[k][tx * 4 + 64];
            float a[8] = {a0.x, a0.y, a0.z, a0.w, a1.x, a1.y, a1.z, a1.w};
            float b[8] = {b0.x, b0.y, b0.z, b0.w, b1.x, b1.y, b1.z, b1.w};
#pragma unroll
            for (int i = 0; i < 8; ++i)
#pragma unroll
                for (int j = 0; j < 8; ++j) acc[i][j] = fmaf(a[i], b[j], acc[i][j]);
        }
        __syncthreads();
    }
#pragma unroll
    for (int i = 0; i < 8; ++i) {
        int row = row0 + ty * 8 + i;
        if (row < nrows) {
            ushort4 c0, c1;
            c0.x = f2bf(acc[i][0]); c0.y = f2bf(acc[i][1]);
            c0.z = f2bf(acc[i][2]); c0.w = f2bf(acc[i][3]);
            c1.x = f2bf(acc[i][4]); c1.y = f2bf(acc[i][5]);
            c1.z = f2bf(acc[i][6]); c1.w = f2bf(acc[i][7]);
            *(ushort4*)&T[(long long)row * H_DIM + tx * 4] = c0;
            *(ushort4*)&T[(long long)row * H_DIM + 64 + tx * 4] = c1;
        }
    }
}

// ---------------------------------------------------------------------------
// GEMM2: T2[N,64] = relu(AGG1[N,128] + b1) @ W2[128,64] -> bf16 output
// ---------------------------------------------------------------------------
__global__ __launch_bounds__(256) void gemm2_kernel(const float* __restrict__ A,
                                                    const float* __restrict__ b1,
                                                    const float* __restrict__ W,
                                                    bf16_t* __restrict__ T,
                                                    int nrows) {
    __shared__ float Xs[16][132];
    __shared__ float Ws[16][64];
    const int t = threadIdx.x;
    const int row0 = blockIdx.x * 128;
    const int ty = t >> 4;
    const int tx = t & 15;

    float acc[8][4];
#pragma unroll
    for (int i = 0; i < 8; ++i)
#pragma unroll
        for (int j = 0; j < 4; ++j) acc[i][j] = 0.0f;

    for (int k0 = 0; k0 < H_DIM; k0 += 16) {
#pragma unroll
        for (int qi = 0; qi < 2; ++qi) {
            int q = t + qi * 256;
            int r = q >> 2, c4 = q & 3;
            int row = row0 + r;
            float4 v = make_float4(0.f, 0.f, 0.f, 0.f);
            if (row < nrows) {
                float4 av = *(const float4*)&A[(long long)row * H_DIM + k0 + c4 * 4];
                float4 bv = *(const float4*)&b1[k0 + c4 * 4];
                v.x = fmaxf(av.x + bv.x, 0.f);
                v.y = fmaxf(av.y + bv.y, 0.f);
                v.z = fmaxf(av.z + bv.z, 0.f);
                v.w = fmaxf(av.w + bv.w, 0.f);
            }
            Xs[c4 * 4 + 0][r] = v.x;
            Xs[c4 * 4 + 1][r] = v.y;
            Xs[c4 * 4 + 2][r] = v.z;
            Xs[c4 * 4 + 3][r] = v.w;
        }
        {
            int r = t >> 4, c4 = t & 15;
            *(float4*)&Ws[r][c4 * 4] = *(const float4*)&W[(k0 + r) * C_DIM + c4 * 4];
        }
        __syncthreads();
#pragma unroll
        for (int k = 0; k < 16; ++k) {
            float4 a0 = *(const float4*)&Xs[k][ty * 8];
            float4 a1 = *(const float4*)&Xs[k][ty * 8 + 4];
            float4 b0 = *(const float4*)&Ws[k][tx * 4];
            float a[8] = {a0.x, a0.y, a0.z, a0.w, a1.x, a1.y, a1.z, a1.w};
            float b[4] = {b0.x, b0.y, b0.z, b0.w};
#pragma unroll
            for (int i = 0; i < 8; ++i)
#pragma unroll
                for (int j = 0; j < 4; ++j) acc[i][j] = fmaf(a[i], b[j], acc[i][j]);
        }
        __syncthreads();
    }
#pragma unroll
    for (int i = 0; i < 8; ++i) {
        int row = row0 + ty * 8 + i;
        if (row < nrows) {
            ushort4 c0;
            c0.x = f2bf(acc[i][0]); c0.y = f2bf(acc[i][1]);
            c0.z = f2bf(acc[i][2]); c0.w = f2bf(acc[i][3]);
            *(ushort4*)&T[(long long)row * C_DIM + tx * 4] = c0;
        }
    }
}

// ---------------------------------------------------------------------------
// Gather aggregation over bf16 t: thread = (node, 8-elem chunk q).
// ---------------------------------------------------------------------------
__device__ inline void fma8_bf16(float* acc, uint4 u, float c) {
#pragma unroll
    for (int p = 0; p < 4; ++p) {
        unsigned w = (&u.x)[p];
        float lo = __uint_as_float(w << 16);
        float hi = __uint_as_float(w & 0xffff0000u);
        acc[2 * p]     = fmaf(lo, c, acc[2 * p]);
        acc[2 * p + 1] = fmaf(hi, c, acc[2 * p + 1]);
    }
}

template <int CS, bool HAS_BIAS>
__global__ __launch_bounds__(256) void agg_kernel(const bf16_t* __restrict__ t,
                                                  const float* __restrict__ dis,
                                                  const int* __restrict__ row_ptr,
                                                  const int* __restrict__ csr_src,
                                                  const float* __restrict__ bias,
                                                  float* __restrict__ agg) {
    unsigned idx = blockIdx.x * 256u + threadIdx.x;
    if (idx >= (unsigned)(N_NODES << CS)) return;
    int node = idx >> CS;
    int q = idx & ((1 << CS) - 1);
    const uint4* tv = (const uint4*)t;
    float dd = dis[node];
    int beg = row_ptr[node], end = row_ptr[node + 1];

    float acc[8];
#pragma unroll
    for (int p = 0; p < 8; ++p) acc[p] = 0.0f;
    fma8_bf16(acc, tv[idx], dd * dd);  // self-loop term

    int j = beg;
    for (; j + 3 < end; j += 4) {
        int s0 = csr_src[j + 0], s1 = csr_src[j + 1];
        int s2 = csr_src[j + 2], s3 = csr_src[j + 3];
        float c0 = dis[s0] * dd, c1 = dis[s1] * dd;
        float c2 = dis[s2] * dd, c3 = dis[s3] * dd;
        uint4 u0 = tv[((unsigned)s0 << CS) + q];
        uint4 u1 = tv[((unsigned)s1 << CS) + q];
        uint4 u2 = tv[((unsigned)s2 << CS) + q];
        uint4 u3 = tv[((unsigned)s3 << CS) + q];
        fma8_bf16(acc, u0, c0);
        fma8_bf16(acc, u1, c1);
        fma8_bf16(acc, u2, c2);
        fma8_bf16(acc, u3, c3);
    }
    for (; j < end; ++j) {
        int s = csr_src[j];
        float c = dis[s] * dd;
        fma8_bf16(acc, tv[((unsigned)s << CS) + q], c);
    }

    if (HAS_BIAS) {
        float4 bv0 = ((const float4*)bias)[q * 2];
        float4 bv1 = ((const float4*)bias)[q * 2 + 1];
        acc[0] += bv0.x; acc[1] += bv0.y; acc[2] += bv0.z; acc[3] += bv0.w;
        acc[4] += bv1.x; acc[5] += bv1.y; acc[6] += bv1.z; acc[7] += bv1.w;
    }
    float4 o0 = make_float4(acc[0], acc[1], acc[2], acc[3]);
    float4 o1 = make_float4(acc[4], acc[5], acc[6], acc[7]);
    ((float4*)agg)[idx * 2]     = o0;
    ((float4*)agg)[idx * 2 + 1] = o1;
}

// ---------------------------------------------------------------------------
// Scoring: 16 lanes per test edge (4 edges/wave); float4 loads, width-16 reduce
// ---------------------------------------------------------------------------
__global__ __launch_bounds__(256) void score_kernel(const float* __restrict__ h2,
                                                    const int* __restrict__ pos,
                                                    const int* __restrict__ neg,
                                                    float* __restrict__ out) {
    int tid = blockIdx.x * 256 + threadIdx.x;
    int e = tid >> 4;
    int q = tid & 15;
    if (e >= 2 * EP_EDGES) return;
    int i, j;
    if (e < EP_EDGES) {
        j = pos[e];
        i = pos[EP_EDGES + e];
    } else {
        j = neg[e - EP_EDGES];
        i = neg[e];
    }
    float4 a = ((const float4*)h2)[i * (C_DIM / 4) + q];
    float4 b = ((const float4*)h2)[j * (C_DIM / 4) + q];
    float v = a.x * b.x + a.y * b.y + a.z * b.z + a.w * b.w;
    v += __shfl_down(v, 8, 16);
    v += __shfl_down(v, 4, 16);
    v += __shfl_down(v, 2, 16);
    v += __shfl_down(v, 1, 16);
    if (q == 0) out[e] = v;
}

// ---------------------------------------------------------------------------
extern "C" void kernel_launch(void* const* d_in, const int* in_sizes, int n_in,
                              void* d_out, int out_size, void* d_ws, size_t ws_size,
                              hipStream_t stream) {
    const float* x  = (const float*)d_in[0];
    const int* pos  = (const int*)d_in[2];
    const int* neg  = (const int*)d_in[3];
    const int* ei   = (const int*)d_in[4];
    const float* W1 = (const float*)d_in[5];
    const float* b1 = (const float*)d_in[6];
    const float* W2 = (const float*)d_in[7];
    const float* b2 = (const float*)d_in[8];
    float* out = (float*)d_out;

    char* ws = (char*)d_ws;
    float*  dis     = (float*) (ws + 0);          //   400,000 B
    int*    row_ptr = (int*)   (ws + 400000);     //   400,004 B
    int*    bcursor = (int*)   (ws + 800128);     //     1,564 B
    int*    csr_src = (int*)   (ws + 801792);     // 6,400,000 B
    int2*   pairs   = (int2*)  (ws + 7201792);    // 12,800,000 B
    bf16_t* t       = (bf16_t*)(ws + 20001792);   // 25,600,000 B (N*128 bf16)
    float*  agg     = (float*) (ws + 45601792);   // 51,200,000 B (N*128 fp32)
    // scan scratch overlaid in agg region (consumed before agg is written):
    int* counts   = (int*)agg;
    int* blocksum = (int*)agg + 131072;

    const int* esrc = ei;
    const int* edst = ei + E_EDGES;
    const int NB = (N_NODES + 255) / 256;      // 391

    // ---- CSR build (also produces dis) ----
    hipMemsetAsync(counts, 0, N_NODES * sizeof(int), stream);
    hist_kernel<<<E_EDGES / 256, 256, 0, stream>>>(edst, counts);
    dis_kernel<<<NB, 256, 0, stream>>>(counts, dis);
    scan1_kernel<<<NB, 256, 0, stream>>>(counts, row_ptr, blocksum);
    scan2_kernel<<<1, 512, 0, stream>>>(blocksum, NB);
    scan3_kernel<<<NB, 256, 0, stream>>>(row_ptr, blocksum);
    binit_kernel<<<1, 512, 0, stream>>>(row_ptr, bcursor);
    bucket_scatter_kernel<<<(E_EDGES + EPB - 1) / EPB, 256, 0, stream>>>(
        esrc, edst, bcursor, pairs);
    bucket_sort_kernel<<<NBUK, 256, 0, stream>>>(pairs, row_ptr, csr_src);

    // ---- layer 1 ----
    gemm1_kernel<<<(N_NODES + 127) / 128, 256, 0, stream>>>(x, W1, t, N_NODES);
    agg_kernel<4, false><<<(N_NODES * 16 + 255) / 256, 256, 0, stream>>>(
        t, dis, row_ptr, csr_src, nullptr, agg);

    // ---- layer 2 ----
    gemm2_kernel<<<(N_NODES + 127) / 128, 256, 0, stream>>>(agg, b1, W2, t, N_NODES);
    agg_kernel<3, true><<<(N_NODES * 8 + 255) / 256, 256, 0, stream>>>(
        t, dis, row_ptr, csr_src, b2, agg);

    // ---- scoring (16 lanes/edge) ----
    score_kernel<<<(2 * EP_EDGES * 16) / 256, 256, 0, stream>>>(agg, pos, neg, out);

    // second output: zeros [2, 2*EP]
    hipMemsetAsync(out + 2 * EP_EDGES, 0, (size_t)4 * EP_EDGES * sizeof(float), stream);
}

// Round 6
// 491.120 us; speedup vs baseline: 9.1332x; 1.0978x over previous
//
#include <hip/hip_runtime.h>

#define N_NODES 100000
#define F_IN    256
#define H_DIM   128
#define C_DIM   64
#define E_EDGES 1600000
#define EP_EDGES 500000

#define NBUK 391          // buckets of 256 nodes: bucket = dst >> 8
#define EPB  4096         // edges per bucket_scatter block

typedef unsigned short bf16_t;
typedef short  short8  __attribute__((ext_vector_type(8)));
typedef float  float4v __attribute__((ext_vector_type(4)));

__device__ inline bf16_t f2bf(float f) {          // round-to-nearest-even
    unsigned u = __float_as_uint(f);
    u += 0x7fff + ((u >> 16) & 1);
    return (bf16_t)(u >> 16);
}
__device__ inline float bf2f(bf16_t h) {
    return __uint_as_float(((unsigned)h) << 16);
}
// split fp32 -> bf16 hi + bf16 lo (x ~ hi + lo, ~2^-17 rel precision)
__device__ inline void split8(const float* vv, short* h, short* l) {
#pragma unroll
    for (int j = 0; j < 8; ++j) {
        bf16_t hb = f2bf(vv[j]);
        h[j] = (short)hb;
        l[j] = (short)f2bf(vv[j] - bf2f(hb));
    }
}
__device__ inline float4v mfma16(short8 a, short8 b, float4v c) {
    return __builtin_amdgcn_mfma_f32_16x16x32_bf16(a, b, c, 0, 0, 0);
}

// ---------------------------------------------------------------------------
// CSR build: histogram -> scan -> bucket scatter -> bucket sort
// ---------------------------------------------------------------------------
__global__ __launch_bounds__(256) void hist_kernel(const int* __restrict__ dst,
                                                   int* __restrict__ counts) {
    int e = blockIdx.x * 256 + threadIdx.x;
    if (e < E_EDGES) atomicAdd(&counts[dst[e]], 1);
}

__global__ __launch_bounds__(256) void dis_kernel(const int* __restrict__ counts,
                                                  float* __restrict__ dis) {
    int i = blockIdx.x * 256 + threadIdx.x;
    if (i < N_NODES) dis[i] = rsqrtf((float)counts[i] + 1.0f);  // +1 self-loop
}

__global__ __launch_bounds__(256) void scan1_kernel(const int* __restrict__ counts,
                                                    int* __restrict__ row_ptr,
                                                    int* __restrict__ blocksum) {
    __shared__ int sh[256];
    int t = threadIdx.x;
    int i = blockIdx.x * 256 + t;
    int v = (i < N_NODES) ? counts[i] : 0;
    sh[t] = v;
    __syncthreads();
#pragma unroll
    for (int off = 1; off < 256; off <<= 1) {
        int u = (t >= off) ? sh[t - off] : 0;
        __syncthreads();
        sh[t] += u;
        __syncthreads();
    }
    if (i < N_NODES) row_ptr[i + 1] = sh[t];
    if (t == 255) blocksum[blockIdx.x] = sh[255];
}

__global__ __launch_bounds__(512) void scan2_kernel(int* __restrict__ blocksum, int nb) {
    __shared__ int sh[512];
    int t = threadIdx.x;
    sh[t] = (t < nb) ? blocksum[t] : 0;
    __syncthreads();
#pragma unroll
    for (int off = 1; off < 512; off <<= 1) {
        int u = (t >= off) ? sh[t - off] : 0;
        __syncthreads();
        sh[t] += u;
        __syncthreads();
    }
    if (t < nb) blocksum[t] = (t == 0) ? 0 : sh[t - 1];
}

__global__ __launch_bounds__(256) void scan3_kernel(int* __restrict__ row_ptr,
                                                    const int* __restrict__ blocksum) {
    int i = blockIdx.x * 256 + threadIdx.x;
    if (i >= N_NODES) return;
    row_ptr[i + 1] += blocksum[blockIdx.x];
    if (i == 0) row_ptr[0] = 0;
}

__global__ __launch_bounds__(512) void binit_kernel(const int* __restrict__ row_ptr,
                                                    int* __restrict__ bcursor) {
    int b = threadIdx.x;
    if (b < NBUK) bcursor[b] = row_ptr[b << 8];
}

__global__ __launch_bounds__(256) void bucket_scatter_kernel(const int* __restrict__ src,
                                                             const int* __restrict__ dst,
                                                             int* __restrict__ bcursor,
                                                             int2* __restrict__ pairs) {
    __shared__ int hist[NBUK];
    __shared__ int base[NBUK];
    const int t = threadIdx.x;
    for (int b = t; b < NBUK; b += 256) hist[b] = 0;
    __syncthreads();

    const int e0 = blockIdx.x * EPB;
    int s[16], d[16];
#pragma unroll
    for (int i = 0; i < 16; ++i) {
        int e = e0 + i * 256 + t;
        if (e < E_EDGES) {
            s[i] = src[e];
            d[i] = dst[e];
            atomicAdd(&hist[d[i] >> 8], 1);
        } else {
            d[i] = -1;
        }
    }
    __syncthreads();
    for (int b = t; b < NBUK; b += 256) {
        int c = hist[b];
        base[b] = c ? atomicAdd(&bcursor[b], c) : 0;
        hist[b] = 0;  // reuse as rank counter
    }
    __syncthreads();
#pragma unroll
    for (int i = 0; i < 16; ++i) {
        if (d[i] >= 0) {
            int b = d[i] >> 8;
            int r = atomicAdd(&hist[b], 1);
            pairs[base[b] + r] = make_int2(s[i], d[i]);
        }
    }
}

__global__ __launch_bounds__(256) void bucket_sort_kernel(const int2* __restrict__ pairs,
                                                          const int* __restrict__ row_ptr,
                                                          int* __restrict__ csr_src) {
    __shared__ int cursor[256];
    const int b = blockIdx.x;
    const int node0 = b << 8;
    const int t = threadIdx.x;
    const int nn = min(256, N_NODES - node0);
    if (t < nn) cursor[t] = row_ptr[node0 + t];
    __syncthreads();
    const int beg = row_ptr[node0];
    const int end = row_ptr[node0 + nn];
    for (int e = beg + t; e < end; e += 256) {
        int2 p = pairs[e];
        int j = atomicAdd(&cursor[p.y - node0], 1);
        csr_src[j] = p.x;
    }
}

// ---------------------------------------------------------------------------
// Weight prep: Wt[n][k] bf16 hi/lo splits for both layers (one-time, tiny)
// ---------------------------------------------------------------------------
__global__ __launch_bounds__(256) void wprep_kernel(const float* __restrict__ W1,
                                                    const float* __restrict__ W2,
                                                    short* __restrict__ w1h,
                                                    short* __restrict__ w1l,
                                                    short* __restrict__ w2h,
                                                    short* __restrict__ w2l) {
    int idx = blockIdx.x * 256 + threadIdx.x;
    if (idx < H_DIM * F_IN) {                    // W1t[n=128][k=256]
        int n = idx >> 8, k = idx & 255;
        float w = W1[k * H_DIM + n];
        bf16_t h = f2bf(w);
        w1h[idx] = (short)h;
        w1l[idx] = (short)f2bf(w - bf2f(h));
    }
    int i2 = idx - H_DIM * F_IN;
    if (i2 >= 0 && i2 < C_DIM * H_DIM) {         // W2t[n=64][k=128]
        int n = i2 >> 7, k = i2 & 127;
        float w = W2[k * C_DIM + n];
        bf16_t h = f2bf(w);
        w2h[i2] = (short)h;
        w2l[i2] = (short)f2bf(w - bf2f(h));
    }
}

// ---------------------------------------------------------------------------
// GEMM1 (MFMA): T[N,128] = X[N,256] @ W1, split-bf16 3-term (~fp32 precision)
// block 256 = 4 waves; tile 128 rows x 128 cols; BK=32; wave = 32 rows x 128
// LDS rows stride 48 shorts (96 B): 16B-aligned b128, <=4-way bank conflict
// ---------------------------------------------------------------------------
__global__ __launch_bounds__(256) void gemm1_mfma(const float* __restrict__ X,
                                                  const short* __restrict__ Wth,
                                                  const short* __restrict__ Wtl,
                                                  bf16_t* __restrict__ T,
                                                  int nrows) {
    __shared__ short Ah[128 * 48], Al[128 * 48];
    __shared__ short Bh[128 * 48], Bl[128 * 48];
    const int t = threadIdx.x;
    const int row0 = blockIdx.x * 128;
    const int w = t >> 6;
    const int lane = t & 63;
    const int m = lane & 15;
    const int q = lane >> 4;
    const int koff = q * 8;

    float4v acc[2][8];
#pragma unroll
    for (int i = 0; i < 2; ++i)
#pragma unroll
        for (int j = 0; j < 8; ++j) acc[i][j] = {0.f, 0.f, 0.f, 0.f};

    for (int ks = 0; ks < 8; ++ks) {
        const int k0 = ks * 32;
        // stage A: 128x32 fp32 -> hi/lo bf16 (512 chunks of 8)
#pragma unroll
        for (int i = 0; i < 2; ++i) {
            int c = t + i * 256;
            int r = c >> 2, kc = c & 3;
            int row = row0 + r;
            float vv[8] = {0.f, 0.f, 0.f, 0.f, 0.f, 0.f, 0.f, 0.f};
            if (row < nrows) {
                float4 v0 = *(const float4*)&X[(long long)row * F_IN + k0 + kc * 8];
                float4 v1 = *(const float4*)&X[(long long)row * F_IN + k0 + kc * 8 + 4];
                vv[0] = v0.x; vv[1] = v0.y; vv[2] = v0.z; vv[3] = v0.w;
                vv[4] = v1.x; vv[5] = v1.y; vv[6] = v1.z; vv[7] = v1.w;
            }
            short h[8], l[8];
            split8(vv, h, l);
            *(short8*)&Ah[r * 48 + kc * 8] = *(short8*)h;
            *(short8*)&Al[r * 48 + kc * 8] = *(short8*)l;
        }
        // stage B: Wt slab 128x32 bf16 hi/lo (straight copy)
#pragma unroll
        for (int i = 0; i < 2; ++i) {
            int c = t + i * 256;
            int n = c >> 2, kc = c & 3;
            *(short8*)&Bh[n * 48 + kc * 8] = *(const short8*)&Wth[n * F_IN + k0 + kc * 8];
            *(short8*)&Bl[n * 48 + kc * 8] = *(const short8*)&Wtl[n * F_IN + k0 + kc * 8];
        }
        __syncthreads();

        short8 ah0 = *(const short8*)&Ah[(w * 32 + m) * 48 + koff];
        short8 ah1 = *(const short8*)&Ah[(w * 32 + 16 + m) * 48 + koff];
        short8 al0 = *(const short8*)&Al[(w * 32 + m) * 48 + koff];
        short8 al1 = *(const short8*)&Al[(w * 32 + 16 + m) * 48 + koff];
#pragma unroll
        for (int nc = 0; nc < 8; ++nc) {
            short8 bh = *(const short8*)&Bh[(nc * 16 + m) * 48 + koff];
            short8 bl = *(const short8*)&Bl[(nc * 16 + m) * 48 + koff];
            acc[0][nc] = mfma16(ah0, bh, acc[0][nc]);
            acc[0][nc] = mfma16(al0, bh, acc[0][nc]);
            acc[0][nc] = mfma16(ah0, bl, acc[0][nc]);
            acc[1][nc] = mfma16(ah1, bh, acc[1][nc]);
            acc[1][nc] = mfma16(al1, bh, acc[1][nc]);
            acc[1][nc] = mfma16(ah1, bl, acc[1][nc]);
        }
        __syncthreads();
    }
    // epilogue: C/D layout col=lane&15, row=(lane>>4)*4+reg
#pragma unroll
    for (int mt = 0; mt < 2; ++mt)
#pragma unroll
        for (int nc = 0; nc < 8; ++nc)
#pragma unroll
            for (int reg = 0; reg < 4; ++reg) {
                int grow = row0 + w * 32 + mt * 16 + q * 4 + reg;
                int gcol = nc * 16 + m;
                if (grow < nrows)
                    T[(long long)grow * H_DIM + gcol] = f2bf(acc[mt][nc][reg]);
            }
}

// ---------------------------------------------------------------------------
// GEMM2 (MFMA): T2[N,64] = relu(AGG1[N,128]+b1) @ W2, split-bf16 3-term
// ---------------------------------------------------------------------------
__global__ __launch_bounds__(256) void gemm2_mfma(const float* __restrict__ A,
                                                  const float* __restrict__ b1,
                                                  const short* __restrict__ Wth,
                                                  const short* __restrict__ Wtl,
                                                  bf16_t* __restrict__ T,
                                                  int nrows) {
    __shared__ short Ah[128 * 48], Al[128 * 48];
    __shared__ short Bh[64 * 48], Bl[64 * 48];
    const int t = threadIdx.x;
    const int row0 = blockIdx.x * 128;
    const int w = t >> 6;
    const int lane = t & 63;
    const int m = lane & 15;
    const int q = lane >> 4;
    const int koff = q * 8;

    float4v acc[2][4];
#pragma unroll
    for (int i = 0; i < 2; ++i)
#pragma unroll
        for (int j = 0; j < 4; ++j) acc[i][j] = {0.f, 0.f, 0.f, 0.f};

    for (int ks = 0; ks < 4; ++ks) {
        const int k0 = ks * 32;
        // stage A: relu(agg + b1) -> hi/lo
#pragma unroll
        for (int i = 0; i < 2; ++i) {
            int c = t + i * 256;
            int r = c >> 2, kc = c & 3;
            int row = row0 + r;
            float vv[8] = {0.f, 0.f, 0.f, 0.f, 0.f, 0.f, 0.f, 0.f};
            if (row < nrows) {
                float4 v0 = *(const float4*)&A[(long long)row * H_DIM + k0 + kc * 8];
                float4 v1 = *(const float4*)&A[(long long)row * H_DIM + k0 + kc * 8 + 4];
                float4 b0 = *(const float4*)&b1[k0 + kc * 8];
                float4 b1v = *(const float4*)&b1[k0 + kc * 8 + 4];
                vv[0] = fmaxf(v0.x + b0.x, 0.f);  vv[1] = fmaxf(v0.y + b0.y, 0.f);
                vv[2] = fmaxf(v0.z + b0.z, 0.f);  vv[3] = fmaxf(v0.w + b0.w, 0.f);
                vv[4] = fmaxf(v1.x + b1v.x, 0.f); vv[5] = fmaxf(v1.y + b1v.y, 0.f);
                vv[6] = fmaxf(v1.z + b1v.z, 0.f); vv[7] = fmaxf(v1.w + b1v.w, 0.f);
            }
            short h[8], l[8];
            split8(vv, h, l);
            *(short8*)&Ah[r * 48 + kc * 8] = *(short8*)h;
            *(short8*)&Al[r * 48 + kc * 8] = *(short8*)l;
        }
        // stage B: W2t slab 64x32 hi/lo (256 chunks each; 1 per thread)
        {
            int n = t >> 2, kc = t & 3;
            *(short8*)&Bh[n * 48 + kc * 8] = *(const short8*)&Wth[n * H_DIM + k0 + kc * 8];
            *(short8*)&Bl[n * 48 + kc * 8] = *(const short8*)&Wtl[n * H_DIM + k0 + kc * 8];
        }
        __syncthreads();

        short8 ah0 = *(const short8*)&Ah[(w * 32 + m) * 48 + koff];
        short8 ah1 = *(const short8*)&Ah[(w * 32 + 16 + m) * 48 + koff];
        short8 al0 = *(const short8*)&Al[(w * 32 + m) * 48 + koff];
        short8 al1 = *(const short8*)&Al[(w * 32 + 16 + m) * 48 + koff];
#pragma unroll
        for (int nc = 0; nc < 4; ++nc) {
            short8 bh = *(const short8*)&Bh[(nc * 16 + m) * 48 + koff];
            short8 bl = *(const short8*)&Bl[(nc * 16 + m) * 48 + koff];
            acc[0][nc] = mfma16(ah0, bh, acc[0][nc]);
            acc[0][nc] = mfma16(al0, bh, acc[0][nc]);
            acc[0][nc] = mfma16(ah0, bl, acc[0][nc]);
            acc[1][nc] = mfma16(ah1, bh, acc[1][nc]);
            acc[1][nc] = mfma16(al1, bh, acc[1][nc]);
            acc[1][nc] = mfma16(ah1, bl, acc[1][nc]);
        }
        __syncthreads();
    }
#pragma unroll
    for (int mt = 0; mt < 2; ++mt)
#pragma unroll
        for (int nc = 0; nc < 4; ++nc)
#pragma unroll
            for (int reg = 0; reg < 4; ++reg) {
                int grow = row0 + w * 32 + mt * 16 + q * 4 + reg;
                int gcol = nc * 16 + m;
                if (grow < nrows)
                    T[(long long)grow * C_DIM + gcol] = f2bf(acc[mt][nc][reg]);
            }
}

// ---------------------------------------------------------------------------
// Gather aggregation over bf16 t: thread = (node, 8-elem chunk q).
// ---------------------------------------------------------------------------
__device__ inline void fma8_bf16(float* acc, uint4 u, float c) {
#pragma unroll
    for (int p = 0; p < 4; ++p) {
        unsigned w = (&u.x)[p];
        float lo = __uint_as_float(w << 16);
        float hi = __uint_as_float(w & 0xffff0000u);
        acc[2 * p]     = fmaf(lo, c, acc[2 * p]);
        acc[2 * p + 1] = fmaf(hi, c, acc[2 * p + 1]);
    }
}

template <int CS, bool HAS_BIAS>
__global__ __launch_bounds__(256) void agg_kernel(const bf16_t* __restrict__ t,
                                                  const float* __restrict__ dis,
                                                  const int* __restrict__ row_ptr,
                                                  const int* __restrict__ csr_src,
                                                  const float* __restrict__ bias,
                                                  float* __restrict__ agg) {
    unsigned idx = blockIdx.x * 256u + threadIdx.x;
    if (idx >= (unsigned)(N_NODES << CS)) return;
    int node = idx >> CS;
    int q = idx & ((1 << CS) - 1);
    const uint4* tv = (const uint4*)t;
    float dd = dis[node];
    int beg = row_ptr[node], end = row_ptr[node + 1];

    float acc[8];
#pragma unroll
    for (int p = 0; p < 8; ++p) acc[p] = 0.0f;
    fma8_bf16(acc, tv[idx], dd * dd);  // self-loop term

    int j = beg;
    for (; j + 3 < end; j += 4) {
        int s0 = csr_src[j + 0], s1 = csr_src[j + 1];
        int s2 = csr_src[j + 2], s3 = csr_src[j + 3];
        float c0 = dis[s0] * dd, c1 = dis[s1] * dd;
        float c2 = dis[s2] * dd, c3 = dis[s3] * dd;
        uint4 u0 = tv[((unsigned)s0 << CS) + q];
        uint4 u1 = tv[((unsigned)s1 << CS) + q];
        uint4 u2 = tv[((unsigned)s2 << CS) + q];
        uint4 u3 = tv[((unsigned)s3 << CS) + q];
        fma8_bf16(acc, u0, c0);
        fma8_bf16(acc, u1, c1);
        fma8_bf16(acc, u2, c2);
        fma8_bf16(acc, u3, c3);
    }
    for (; j < end; ++j) {
        int s = csr_src[j];
        float c = dis[s] * dd;
        fma8_bf16(acc, tv[((unsigned)s << CS) + q], c);
    }

    if (HAS_BIAS) {
        float4 bv0 = ((const float4*)bias)[q * 2];
        float4 bv1 = ((const float4*)bias)[q * 2 + 1];
        acc[0] += bv0.x; acc[1] += bv0.y; acc[2] += bv0.z; acc[3] += bv0.w;
        acc[4] += bv1.x; acc[5] += bv1.y; acc[6] += bv1.z; acc[7] += bv1.w;
    }
    float4 o0 = make_float4(acc[0], acc[1], acc[2], acc[3]);
    float4 o1 = make_float4(acc[4], acc[5], acc[6], acc[7]);
    ((float4*)agg)[idx * 2]     = o0;
    ((float4*)agg)[idx * 2 + 1] = o1;
}

// ---------------------------------------------------------------------------
// Scoring: 16 lanes per test edge (4 edges/wave); float4 loads, width-16 reduce
// ---------------------------------------------------------------------------
__global__ __launch_bounds__(256) void score_kernel(const float* __restrict__ h2,
                                                    const int* __restrict__ pos,
                                                    const int* __restrict__ neg,
                                                    float* __restrict__ out) {
    int tid = blockIdx.x * 256 + threadIdx.x;
    int e = tid >> 4;
    int q = tid & 15;
    if (e >= 2 * EP_EDGES) return;
    int i, j;
    if (e < EP_EDGES) {
        j = pos[e];
        i = pos[EP_EDGES + e];
    } else {
        j = neg[e - EP_EDGES];
        i = neg[e];
    }
    float4 a = ((const float4*)h2)[i * (C_DIM / 4) + q];
    float4 b = ((const float4*)h2)[j * (C_DIM / 4) + q];
    float v = a.x * b.x + a.y * b.y + a.z * b.z + a.w * b.w;
    v += __shfl_down(v, 8, 16);
    v += __shfl_down(v, 4, 16);
    v += __shfl_down(v, 2, 16);
    v += __shfl_down(v, 1, 16);
    if (q == 0) out[e] = v;
}

// ---------------------------------------------------------------------------
extern "C" void kernel_launch(void* const* d_in, const int* in_sizes, int n_in,
                              void* d_out, int out_size, void* d_ws, size_t ws_size,
                              hipStream_t stream) {
    const float* x  = (const float*)d_in[0];
    const int* pos  = (const int*)d_in[2];
    const int* neg  = (const int*)d_in[3];
    const int* ei   = (const int*)d_in[4];
    const float* W1 = (const float*)d_in[5];
    const float* b1 = (const float*)d_in[6];
    const float* W2 = (const float*)d_in[7];
    const float* b2 = (const float*)d_in[8];
    float* out = (float*)d_out;

    char* ws = (char*)d_ws;
    float*  dis     = (float*) (ws + 0);          //   400,000 B
    int*    row_ptr = (int*)   (ws + 400000);     //   400,004 B
    int*    bcursor = (int*)   (ws + 800128);     //     1,564 B
    int*    csr_src = (int*)   (ws + 801792);     // 6,400,000 B
    int2*   pairs   = (int2*)  (ws + 7201792);    // 12,800,000 B
    bf16_t* t       = (bf16_t*)(ws + 20001792);   // 25,600,000 B (N*128 bf16)
    float*  agg     = (float*) (ws + 45601792);   // 51,200,000 B (N*128 fp32)
    short*  w1th    = (short*) (ws + 96801792);   // 65,536 B (W1t hi [128][256])
    short*  w1tl    = (short*) (ws + 96867328);   // 65,536 B
    short*  w2th    = (short*) (ws + 96932864);   // 16,384 B (W2t hi [64][128])
    short*  w2tl    = (short*) (ws + 96949248);   // 16,384 B -> end 96,965,632
    // scan scratch overlaid in agg region (consumed before agg is written):
    int* counts   = (int*)agg;
    int* blocksum = (int*)agg + 131072;

    const int* esrc = ei;
    const int* edst = ei + E_EDGES;
    const int NB = (N_NODES + 255) / 256;      // 391

    // ---- CSR build (also produces dis) + weight prep ----
    hipMemsetAsync(counts, 0, N_NODES * sizeof(int), stream);
    hist_kernel<<<E_EDGES / 256, 256, 0, stream>>>(edst, counts);
    dis_kernel<<<NB, 256, 0, stream>>>(counts, dis);
    scan1_kernel<<<NB, 256, 0, stream>>>(counts, row_ptr, blocksum);
    scan2_kernel<<<1, 512, 0, stream>>>(blocksum, NB);
    scan3_kernel<<<NB, 256, 0, stream>>>(row_ptr, blocksum);
    binit_kernel<<<1, 512, 0, stream>>>(row_ptr, bcursor);
    bucket_scatter_kernel<<<(E_EDGES + EPB - 1) / EPB, 256, 0, stream>>>(
        esrc, edst, bcursor, pairs);
    bucket_sort_kernel<<<NBUK, 256, 0, stream>>>(pairs, row_ptr, csr_src);
    wprep_kernel<<<(H_DIM * F_IN + C_DIM * H_DIM + 255) / 256, 256, 0, stream>>>(
        W1, W2, w1th, w1tl, w2th, w2tl);

    // ---- layer 1 ----
    gemm1_mfma<<<(N_NODES + 127) / 128, 256, 0, stream>>>(x, w1th, w1tl, t, N_NODES);
    agg_kernel<4, false><<<(N_NODES * 16 + 255) / 256, 256, 0, stream>>>(
        t, dis, row_ptr, csr_src, nullptr, agg);

    // ---- layer 2 ----
    gemm2_mfma<<<(N_NODES + 127) / 128, 256, 0, stream>>>(agg, b1, w2th, w2tl, t, N_NODES);
    agg_kernel<3, true><<<(N_NODES * 8 + 255) / 256, 256, 0, stream>>>(
        t, dis, row_ptr, csr_src, b2, agg);

    // ---- scoring (16 lanes/edge) ----
    score_kernel<<<(2 * EP_EDGES * 16) / 256, 256, 0, stream>>>(agg, pos, neg, out);

    // second output: zeros [2, 2*EP]
    hipMemsetAsync(out + 2 * EP_EDGES, 0, (size_t)4 * EP_EDGES * sizeof(float), stream);
}

// Round 7
// 438.781 us; speedup vs baseline: 10.2226x; 1.1193x over previous
//
#include <hip/hip_runtime.h>

#define N_NODES 100000
#define F_IN    256
#define H_DIM   128
#define C_DIM   64
#define E_EDGES 1600000
#define EP_EDGES 500000

#define NBUK 391          // buckets of 256 nodes: bucket = dst >> 8
#define EPB  4096         // edges per bucket-pass block

typedef unsigned short bf16_t;
typedef short  short8  __attribute__((ext_vector_type(8)));
typedef float  float4v __attribute__((ext_vector_type(4)));

__device__ inline bf16_t f2bf(float f) {          // round-to-nearest-even
    unsigned u = __float_as_uint(f);
    u += 0x7fff + ((u >> 16) & 1);
    return (bf16_t)(u >> 16);
}
__device__ inline float bf2f(bf16_t h) {
    return __uint_as_float(((unsigned)h) << 16);
}
__device__ inline void split8(const float* vv, short* h, short* l) {
#pragma unroll
    for (int j = 0; j < 8; ++j) {
        bf16_t hb = f2bf(vv[j]);
        h[j] = (short)hb;
        l[j] = (short)f2bf(vv[j] - bf2f(hb));
    }
}
__device__ inline float4v mfma16(short8 a, short8 b, float4v c) {
    return __builtin_amdgcn_mfma_f32_16x16x32_bf16(a, b, c, 0, 0, 0);
}

// ---------------------------------------------------------------------------
// CSR build v2: bucket hist -> bucket scan -> bucket scatter -> bucket sort
// (per-node counts/row_ptr/dis all derived inside buckets via LDS — no global
//  per-node atomics anywhere)
// ---------------------------------------------------------------------------
__global__ __launch_bounds__(256) void bhist_kernel(const int* __restrict__ dst,
                                                    int* __restrict__ bsize) {
    __shared__ int hist[NBUK];
    const int t = threadIdx.x;
    for (int b = t; b < NBUK; b += 256) hist[b] = 0;
    __syncthreads();
    const int e0 = blockIdx.x * EPB;
#pragma unroll
    for (int i = 0; i < 16; ++i) {
        int e = e0 + i * 256 + t;
        if (e < E_EDGES) atomicAdd(&hist[dst[e] >> 8], 1);
    }
    __syncthreads();
    for (int b = t; b < NBUK; b += 256)
        if (hist[b]) atomicAdd(&bsize[b], hist[b]);
}

__global__ __launch_bounds__(512) void bscan_kernel(const int* __restrict__ bsize,
                                                    int* __restrict__ bbase,
                                                    int* __restrict__ bcursor) {
    __shared__ int sh[512];
    int t = threadIdx.x;
    sh[t] = (t < NBUK) ? bsize[t] : 0;
    __syncthreads();
#pragma unroll
    for (int off = 1; off < 512; off <<= 1) {
        int u = (t >= off) ? sh[t - off] : 0;
        __syncthreads();
        sh[t] += u;
        __syncthreads();
    }
    if (t < NBUK) {
        int ex = (t == 0) ? 0 : sh[t - 1];
        bbase[t] = ex;
        bcursor[t] = ex;
    }
    if (t == 0) bbase[NBUK] = E_EDGES;
}

__global__ __launch_bounds__(256) void bucket_scatter_kernel(const int* __restrict__ src,
                                                             const int* __restrict__ dst,
                                                             int* __restrict__ bcursor,
                                                             int2* __restrict__ pairs) {
    __shared__ int hist[NBUK];
    __shared__ int base[NBUK];
    const int t = threadIdx.x;
    for (int b = t; b < NBUK; b += 256) hist[b] = 0;
    __syncthreads();

    const int e0 = blockIdx.x * EPB;
    int s[16], d[16];
#pragma unroll
    for (int i = 0; i < 16; ++i) {
        int e = e0 + i * 256 + t;
        if (e < E_EDGES) {
            s[i] = src[e];
            d[i] = dst[e];
            atomicAdd(&hist[d[i] >> 8], 1);
        } else {
            d[i] = -1;
        }
    }
    __syncthreads();
    for (int b = t; b < NBUK; b += 256) {
        int c = hist[b];
        base[b] = c ? atomicAdd(&bcursor[b], c) : 0;
        hist[b] = 0;  // reuse as rank counter
    }
    __syncthreads();
#pragma unroll
    for (int i = 0; i < 16; ++i) {
        if (d[i] >= 0) {
            int b = d[i] >> 8;
            int r = atomicAdd(&hist[b], 1);
            pairs[base[b] + r] = make_int2(s[i], d[i]);
        }
    }
}

// One block per bucket: LDS-count nodes, emit dis + row_ptr, counting-sort csr.
__global__ __launch_bounds__(256) void bucket_sort_kernel(const int2* __restrict__ pairs,
                                                          const int* __restrict__ bbase,
                                                          int* __restrict__ row_ptr,
                                                          float* __restrict__ dis,
                                                          int* __restrict__ csr_src) {
    __shared__ int cnt[256];
    __shared__ int sh[256];
    __shared__ int cur[256];
    const int b = blockIdx.x;
    const int node0 = b << 8;
    const int t = threadIdx.x;
    const int nn = min(256, N_NODES - node0);
    const int beg = bbase[b], end = bbase[b + 1];
    cnt[t] = 0;
    __syncthreads();
    for (int e = beg + t; e < end; e += 256)
        atomicAdd(&cnt[pairs[e].y - node0], 1);
    __syncthreads();
    int c = cnt[t];
    if (t < nn) dis[node0 + t] = rsqrtf((float)c + 1.0f);
    sh[t] = c;
    __syncthreads();
#pragma unroll
    for (int off = 1; off < 256; off <<= 1) {
        int u = (t >= off) ? sh[t - off] : 0;
        __syncthreads();
        sh[t] += u;
        __syncthreads();
    }
    int start = beg + sh[t] - c;   // exclusive prefix
    if (t < nn) row_ptr[node0 + t] = start;
    cur[t] = start;
    if (b == NBUK - 1 && t == 0) row_ptr[N_NODES] = E_EDGES;
    __syncthreads();
    for (int e = beg + t; e < end; e += 256) {
        int2 p = pairs[e];
        int j = atomicAdd(&cur[p.y - node0], 1);
        csr_src[j] = p.x;
    }
}

// ---------------------------------------------------------------------------
// Weight prep: Wt[n][k] bf16 hi/lo splits for both layers (one-time, tiny)
// ---------------------------------------------------------------------------
__global__ __launch_bounds__(256) void wprep_kernel(const float* __restrict__ W1,
                                                    const float* __restrict__ W2,
                                                    short* __restrict__ w1h,
                                                    short* __restrict__ w1l,
                                                    short* __restrict__ w2h,
                                                    short* __restrict__ w2l) {
    int idx = blockIdx.x * 256 + threadIdx.x;
    if (idx < H_DIM * F_IN) {                    // W1t[n=128][k=256]
        int n = idx >> 8, k = idx & 255;
        float w = W1[k * H_DIM + n];
        bf16_t h = f2bf(w);
        w1h[idx] = (short)h;
        w1l[idx] = (short)f2bf(w - bf2f(h));
    }
    int i2 = idx - H_DIM * F_IN;
    if (i2 >= 0 && i2 < C_DIM * H_DIM) {         // W2t[n=64][k=128]
        int n = i2 >> 7, k = i2 & 127;
        float w = W2[k * C_DIM + n];
        bf16_t h = f2bf(w);
        w2h[i2] = (short)h;
        w2l[i2] = (short)f2bf(w - bf2f(h));
    }
}

// ---------------------------------------------------------------------------
// GEMM1 (MFMA): T[N,128] = X[N,256] @ W1, split-bf16 3-term (~fp32 precision)
// LDS row stride 40 shorts (80 B, 16B-aligned); total LDS 40960 B -> 4 blk/CU
// ---------------------------------------------------------------------------
#define LSTR 40
__global__ __launch_bounds__(256) void gemm1_mfma(const float* __restrict__ X,
                                                  const short* __restrict__ Wth,
                                                  const short* __restrict__ Wtl,
                                                  bf16_t* __restrict__ T,
                                                  int nrows) {
    __shared__ short Ah[128 * LSTR], Al[128 * LSTR];
    __shared__ short Bh[128 * LSTR], Bl[128 * LSTR];
    const int t = threadIdx.x;
    const int row0 = blockIdx.x * 128;
    const int w = t >> 6;
    const int lane = t & 63;
    const int m = lane & 15;
    const int q = lane >> 4;
    const int koff = q * 8;

    float4v acc[2][8];
#pragma unroll
    for (int i = 0; i < 2; ++i)
#pragma unroll
        for (int j = 0; j < 8; ++j) acc[i][j] = {0.f, 0.f, 0.f, 0.f};

    for (int ks = 0; ks < 8; ++ks) {
        const int k0 = ks * 32;
#pragma unroll
        for (int i = 0; i < 2; ++i) {
            int c = t + i * 256;
            int r = c >> 2, kc = c & 3;
            int row = row0 + r;
            float vv[8] = {0.f, 0.f, 0.f, 0.f, 0.f, 0.f, 0.f, 0.f};
            if (row < nrows) {
                float4 v0 = *(const float4*)&X[(long long)row * F_IN + k0 + kc * 8];
                float4 v1 = *(const float4*)&X[(long long)row * F_IN + k0 + kc * 8 + 4];
                vv[0] = v0.x; vv[1] = v0.y; vv[2] = v0.z; vv[3] = v0.w;
                vv[4] = v1.x; vv[5] = v1.y; vv[6] = v1.z; vv[7] = v1.w;
            }
            short h[8], l[8];
            split8(vv, h, l);
            *(short8*)&Ah[r * LSTR + kc * 8] = *(short8*)h;
            *(short8*)&Al[r * LSTR + kc * 8] = *(short8*)l;
        }
#pragma unroll
        for (int i = 0; i < 2; ++i) {
            int c = t + i * 256;
            int n = c >> 2, kc = c & 3;
            *(short8*)&Bh[n * LSTR + kc * 8] = *(const short8*)&Wth[n * F_IN + k0 + kc * 8];
            *(short8*)&Bl[n * LSTR + kc * 8] = *(const short8*)&Wtl[n * F_IN + k0 + kc * 8];
        }
        __syncthreads();

        short8 ah0 = *(const short8*)&Ah[(w * 32 + m) * LSTR + koff];
        short8 ah1 = *(const short8*)&Ah[(w * 32 + 16 + m) * LSTR + koff];
        short8 al0 = *(const short8*)&Al[(w * 32 + m) * LSTR + koff];
        short8 al1 = *(const short8*)&Al[(w * 32 + 16 + m) * LSTR + koff];
#pragma unroll
        for (int nc = 0; nc < 8; ++nc) {
            short8 bh = *(const short8*)&Bh[(nc * 16 + m) * LSTR + koff];
            short8 bl = *(const short8*)&Bl[(nc * 16 + m) * LSTR + koff];
            acc[0][nc] = mfma16(ah0, bh, acc[0][nc]);
            acc[0][nc] = mfma16(al0, bh, acc[0][nc]);
            acc[0][nc] = mfma16(ah0, bl, acc[0][nc]);
            acc[1][nc] = mfma16(ah1, bh, acc[1][nc]);
            acc[1][nc] = mfma16(al1, bh, acc[1][nc]);
            acc[1][nc] = mfma16(ah1, bl, acc[1][nc]);
        }
        __syncthreads();
    }
#pragma unroll
    for (int mt = 0; mt < 2; ++mt)
#pragma unroll
        for (int nc = 0; nc < 8; ++nc)
#pragma unroll
            for (int reg = 0; reg < 4; ++reg) {
                int grow = row0 + w * 32 + mt * 16 + q * 4 + reg;
                int gcol = nc * 16 + m;
                if (grow < nrows)
                    T[(long long)grow * H_DIM + gcol] = f2bf(acc[mt][nc][reg]);
            }
}

// ---------------------------------------------------------------------------
// GEMM2 (MFMA): T2[N,64] = relu(AGG1[N,128]+b1) @ W2, split-bf16 3-term
// ---------------------------------------------------------------------------
__global__ __launch_bounds__(256) void gemm2_mfma(const float* __restrict__ A,
                                                  const float* __restrict__ b1,
                                                  const short* __restrict__ Wth,
                                                  const short* __restrict__ Wtl,
                                                  bf16_t* __restrict__ T,
                                                  int nrows) {
    __shared__ short Ah[128 * LSTR], Al[128 * LSTR];
    __shared__ short Bh[64 * LSTR], Bl[64 * LSTR];
    const int t = threadIdx.x;
    const int row0 = blockIdx.x * 128;
    const int w = t >> 6;
    const int lane = t & 63;
    const int m = lane & 15;
    const int q = lane >> 4;
    const int koff = q * 8;

    float4v acc[2][4];
#pragma unroll
    for (int i = 0; i < 2; ++i)
#pragma unroll
        for (int j = 0; j < 4; ++j) acc[i][j] = {0.f, 0.f, 0.f, 0.f};

    for (int ks = 0; ks < 4; ++ks) {
        const int k0 = ks * 32;
#pragma unroll
        for (int i = 0; i < 2; ++i) {
            int c = t + i * 256;
            int r = c >> 2, kc = c & 3;
            int row = row0 + r;
            float vv[8] = {0.f, 0.f, 0.f, 0.f, 0.f, 0.f, 0.f, 0.f};
            if (row < nrows) {
                float4 v0 = *(const float4*)&A[(long long)row * H_DIM + k0 + kc * 8];
                float4 v1 = *(const float4*)&A[(long long)row * H_DIM + k0 + kc * 8 + 4];
                float4 b0 = *(const float4*)&b1[k0 + kc * 8];
                float4 b1v = *(const float4*)&b1[k0 + kc * 8 + 4];
                vv[0] = fmaxf(v0.x + b0.x, 0.f);  vv[1] = fmaxf(v0.y + b0.y, 0.f);
                vv[2] = fmaxf(v0.z + b0.z, 0.f);  vv[3] = fmaxf(v0.w + b0.w, 0.f);
                vv[4] = fmaxf(v1.x + b1v.x, 0.f); vv[5] = fmaxf(v1.y + b1v.y, 0.f);
                vv[6] = fmaxf(v1.z + b1v.z, 0.f); vv[7] = fmaxf(v1.w + b1v.w, 0.f);
            }
            short h[8], l[8];
            split8(vv, h, l);
            *(short8*)&Ah[r * LSTR + kc * 8] = *(short8*)h;
            *(short8*)&Al[r * LSTR + kc * 8] = *(short8*)l;
        }
        {
            int n = t >> 2, kc = t & 3;
            *(short8*)&Bh[n * LSTR + kc * 8] = *(const short8*)&Wth[n * H_DIM + k0 + kc * 8];
            *(short8*)&Bl[n * LSTR + kc * 8] = *(const short8*)&Wtl[n * H_DIM + k0 + kc * 8];
        }
        __syncthreads();

        short8 ah0 = *(const short8*)&Ah[(w * 32 + m) * LSTR + koff];
        short8 ah1 = *(const short8*)&Ah[(w * 32 + 16 + m) * LSTR + koff];
        short8 al0 = *(const short8*)&Al[(w * 32 + m) * LSTR + koff];
        short8 al1 = *(const short8*)&Al[(w * 32 + 16 + m) * LSTR + koff];
#pragma unroll
        for (int nc = 0; nc < 4; ++nc) {
            short8 bh = *(const short8*)&Bh[(nc * 16 + m) * LSTR + koff];
            short8 bl = *(const short8*)&Bl[(nc * 16 + m) * LSTR + koff];
            acc[0][nc] = mfma16(ah0, bh, acc[0][nc]);
            acc[0][nc] = mfma16(al0, bh, acc[0][nc]);
            acc[0][nc] = mfma16(ah0, bl, acc[0][nc]);
            acc[1][nc] = mfma16(ah1, bh, acc[1][nc]);
            acc[1][nc] = mfma16(al1, bh, acc[1][nc]);
            acc[1][nc] = mfma16(ah1, bl, acc[1][nc]);
        }
        __syncthreads();
    }
#pragma unroll
    for (int mt = 0; mt < 2; ++mt)
#pragma unroll
        for (int nc = 0; nc < 4; ++nc)
#pragma unroll
            for (int reg = 0; reg < 4; ++reg) {
                int grow = row0 + w * 32 + mt * 16 + q * 4 + reg;
                int gcol = nc * 16 + m;
                if (grow < nrows)
                    T[(long long)grow * C_DIM + gcol] = f2bf(acc[mt][nc][reg]);
            }
}

// ---------------------------------------------------------------------------
// Gather aggregation over bf16 t: thread = (node, 8-elem chunk q).
// ---------------------------------------------------------------------------
__device__ inline void fma8_bf16(float* acc, uint4 u, float c) {
#pragma unroll
    for (int p = 0; p < 4; ++p) {
        unsigned w = (&u.x)[p];
        float lo = __uint_as_float(w << 16);
        float hi = __uint_as_float(w & 0xffff0000u);
        acc[2 * p]     = fmaf(lo, c, acc[2 * p]);
        acc[2 * p + 1] = fmaf(hi, c, acc[2 * p + 1]);
    }
}

template <int CS, bool HAS_BIAS>
__global__ __launch_bounds__(256) void agg_kernel(const bf16_t* __restrict__ t,
                                                  const float* __restrict__ dis,
                                                  const int* __restrict__ row_ptr,
                                                  const int* __restrict__ csr_src,
                                                  const float* __restrict__ bias,
                                                  float* __restrict__ agg) {
    unsigned idx = blockIdx.x * 256u + threadIdx.x;
    if (idx >= (unsigned)(N_NODES << CS)) return;
    int node = idx >> CS;
    int q = idx & ((1 << CS) - 1);
    const uint4* tv = (const uint4*)t;
    float dd = dis[node];
    int beg = row_ptr[node], end = row_ptr[node + 1];

    float acc[8];
#pragma unroll
    for (int p = 0; p < 8; ++p) acc[p] = 0.0f;
    fma8_bf16(acc, tv[idx], dd * dd);  // self-loop term

    int j = beg;
    for (; j + 3 < end; j += 4) {
        int s0 = csr_src[j + 0], s1 = csr_src[j + 1];
        int s2 = csr_src[j + 2], s3 = csr_src[j + 3];
        float c0 = dis[s0] * dd, c1 = dis[s1] * dd;
        float c2 = dis[s2] * dd, c3 = dis[s3] * dd;
        uint4 u0 = tv[((unsigned)s0 << CS) + q];
        uint4 u1 = tv[((unsigned)s1 << CS) + q];
        uint4 u2 = tv[((unsigned)s2 << CS) + q];
        uint4 u3 = tv[((unsigned)s3 << CS) + q];
        fma8_bf16(acc, u0, c0);
        fma8_bf16(acc, u1, c1);
        fma8_bf16(acc, u2, c2);
        fma8_bf16(acc, u3, c3);
    }
    for (; j < end; ++j) {
        int s = csr_src[j];
        float c = dis[s] * dd;
        fma8_bf16(acc, tv[((unsigned)s << CS) + q], c);
    }

    if (HAS_BIAS) {
        float4 bv0 = ((const float4*)bias)[q * 2];
        float4 bv1 = ((const float4*)bias)[q * 2 + 1];
        acc[0] += bv0.x; acc[1] += bv0.y; acc[2] += bv0.z; acc[3] += bv0.w;
        acc[4] += bv1.x; acc[5] += bv1.y; acc[6] += bv1.z; acc[7] += bv1.w;
    }
    float4 o0 = make_float4(acc[0], acc[1], acc[2], acc[3]);
    float4 o1 = make_float4(acc[4], acc[5], acc[6], acc[7]);
    ((float4*)agg)[idx * 2]     = o0;
    ((float4*)agg)[idx * 2 + 1] = o1;
}

// ---------------------------------------------------------------------------
// Scoring: 16 lanes per test edge (4 edges/wave); float4 loads, width-16 reduce
// ---------------------------------------------------------------------------
__global__ __launch_bounds__(256) void score_kernel(const float* __restrict__ h2,
                                                    const int* __restrict__ pos,
                                                    const int* __restrict__ neg,
                                                    float* __restrict__ out) {
    int tid = blockIdx.x * 256 + threadIdx.x;
    int e = tid >> 4;
    int q = tid & 15;
    if (e >= 2 * EP_EDGES) return;
    int i, j;
    if (e < EP_EDGES) {
        j = pos[e];
        i = pos[EP_EDGES + e];
    } else {
        j = neg[e - EP_EDGES];
        i = neg[e];
    }
    float4 a = ((const float4*)h2)[i * (C_DIM / 4) + q];
    float4 b = ((const float4*)h2)[j * (C_DIM / 4) + q];
    float v = a.x * b.x + a.y * b.y + a.z * b.z + a.w * b.w;
    v += __shfl_down(v, 8, 16);
    v += __shfl_down(v, 4, 16);
    v += __shfl_down(v, 2, 16);
    v += __shfl_down(v, 1, 16);
    if (q == 0) out[e] = v;
}

// ---------------------------------------------------------------------------
extern "C" void kernel_launch(void* const* d_in, const int* in_sizes, int n_in,
                              void* d_out, int out_size, void* d_ws, size_t ws_size,
                              hipStream_t stream) {
    const float* x  = (const float*)d_in[0];
    const int* pos  = (const int*)d_in[2];
    const int* neg  = (const int*)d_in[3];
    const int* ei   = (const int*)d_in[4];
    const float* W1 = (const float*)d_in[5];
    const float* b1 = (const float*)d_in[6];
    const float* W2 = (const float*)d_in[7];
    const float* b2 = (const float*)d_in[8];
    float* out = (float*)d_out;

    char* ws = (char*)d_ws;
    float*  dis     = (float*) (ws + 0);          //   400,000 B
    int*    row_ptr = (int*)   (ws + 400000);     //   400,004 B
    int*    bsize   = (int*)   (ws + 800128);     //     1,564 B
    int*    bbase   = (int*)   (ws + 801792);     //     1,568 B
    int*    bcursor = (int*)   (ws + 803456);     //     1,564 B
    int*    csr_src = (int*)   (ws + 805120);     // 6,400,000 B
    int2*   pairs   = (int2*)  (ws + 7205120);    // 12,800,000 B
    bf16_t* t       = (bf16_t*)(ws + 20005120);   // 25,600,000 B (N*128 bf16)
    float*  agg     = (float*) (ws + 45605120);   // 51,200,000 B (N*128 fp32)
    short*  w1th    = (short*) (ws + 96805120);   // 65,536 B
    short*  w1tl    = (short*) (ws + 96870656);   // 65,536 B
    short*  w2th    = (short*) (ws + 96936192);   // 16,384 B
    short*  w2tl    = (short*) (ws + 96952576);   // 16,384 B -> end 96,968,960

    const int* esrc = ei;
    const int* edst = ei + E_EDGES;

    // ---- CSR build v2 (bucketed; produces row_ptr, dis, csr_src) ----
    hipMemsetAsync(bsize, 0, NBUK * sizeof(int), stream);
    bhist_kernel<<<(E_EDGES + EPB - 1) / EPB, 256, 0, stream>>>(edst, bsize);
    bscan_kernel<<<1, 512, 0, stream>>>(bsize, bbase, bcursor);
    bucket_scatter_kernel<<<(E_EDGES + EPB - 1) / EPB, 256, 0, stream>>>(
        esrc, edst, bcursor, pairs);
    bucket_sort_kernel<<<NBUK, 256, 0, stream>>>(pairs, bbase, row_ptr, dis, csr_src);
    wprep_kernel<<<(H_DIM * F_IN + C_DIM * H_DIM + 255) / 256, 256, 0, stream>>>(
        W1, W2, w1th, w1tl, w2th, w2tl);

    // ---- layer 1 ----
    gemm1_mfma<<<(N_NODES + 127) / 128, 256, 0, stream>>>(x, w1th, w1tl, t, N_NODES);
    agg_kernel<4, false><<<(N_NODES * 16 + 255) / 256, 256, 0, stream>>>(
        t, dis, row_ptr, csr_src, nullptr, agg);

    // ---- layer 2 ----
    gemm2_mfma<<<(N_NODES + 127) / 128, 256, 0, stream>>>(agg, b1, w2th, w2tl, t, N_NODES);
    agg_kernel<3, true><<<(N_NODES * 8 + 255) / 256, 256, 0, stream>>>(
        t, dis, row_ptr, csr_src, b2, agg);

    // ---- scoring (16 lanes/edge) ----
    score_kernel<<<(2 * EP_EDGES * 16) / 256, 256, 0, stream>>>(agg, pos, neg, out);

    // second output: zeros [2, 2*EP]
    hipMemsetAsync(out + 2 * EP_EDGES, 0, (size_t)4 * EP_EDGES * sizeof(float), stream);
}